// Round 14
// baseline (919.097 us; speedup 1.0000x reference)
//
#include <hip/hip_runtime.h>
#include <math.h>

#define BNF 0.9999950000374997f

constexpr int N    = 2048;
constexpr int C    = 200;
constexpr int HW   = 65536;
constexpr int MAXDEG = 96;

typedef unsigned short u16;
typedef __attribute__((ext_vector_type(8))) short short8;
typedef __attribute__((ext_vector_type(4))) float f32x4;

union Frag  { short8 v; ushort4 h[2]; };
union FragA { short8 v; uint2 u2[2]; };

__device__ inline u16 f2bf(float x) {
    unsigned int u = __float_as_uint(x);
    unsigned int r = (u + 0x7fffu + ((u >> 16) & 1u)) >> 16;
    return (u16)r;
}

__device__ __forceinline__ void gload16(const void* g, void* l) {
    __builtin_amdgcn_global_load_lds(
        (const __attribute__((address_space(1))) unsigned int*)g,
        (__attribute__((address_space(3))) unsigned int*)l, 16, 0, 0);
}

// ---------------------------------------------------------------------------
// blocks 0..511: xf -> xfT [208][65536] bf16 (rows 200..207 zeroed)
// blocks 512..1023: CSR build
// ---------------------------------------------------------------------------
__global__ __launch_bounds__(256) void k_convX(const float* __restrict__ xf,
                                               u16* __restrict__ xfT,
                                               const float* __restrict__ adj,
                                               int* __restrict__ deg,
                                               int* __restrict__ idxs) {
    const int t = threadIdx.x;
    if (blockIdx.x >= 512) {
        int w = t >> 6, lane = t & 63;
        int n = (blockIdx.x - 512) * 4 + w;
        const float* row = adj + (size_t)n * N;
        int base = 0;
        for (int c = 0; c < N; c += 64) {
            float v = row[c + lane];
            bool p = v > 0.f;
            unsigned long long m = __ballot(p);
            int pos = __popcll(m & ((1ull << lane) - 1ull));
            if (p && (base + pos) < MAXDEG)
                idxs[(size_t)n * MAXDEG + base + pos] = c + lane;
            base += __popcll(m);
        }
        if (lane == 0) deg[n] = base < MAXDEG ? base : MAXDEG;
        return;
    }
    __shared__ __align__(16) u16 T2[200][140];
    const int i0 = blockIdx.x * 128;
    for (int p = 0; p < 25; ++p) {
        int idx = p * 256 + t;
        int il = idx / 50, cq = idx % 50;
        float4 v = *(const float4*)&xf[(size_t)(i0 + il) * 200 + cq * 4];
        T2[cq * 4 + 0][il] = f2bf(v.x);
        T2[cq * 4 + 1][il] = f2bf(v.y);
        T2[cq * 4 + 2][il] = f2bf(v.z);
        T2[cq * 4 + 3][il] = f2bf(v.w);
    }
    __syncthreads();
    for (int p = 0; p < 13; ++p) {
        int c = p * 16 + (t >> 4);
        if (c < 200) {
            int io = (t & 15) * 8;
            u16* dst = &xfT[(size_t)c * 65536 + i0 + io];
            *(ushort4*)&dst[0] = *(const ushort4*)&T2[c][io];
            *(ushort4*)&dst[4] = *(const ushort4*)&T2[c][io + 4];
        }
    }
    ushort4 z4 = {0, 0, 0, 0};
    for (int idx = t; idx < 8 * 16; idx += 256) {
        int r = 200 + (idx >> 4), io = (idx & 15) * 8;
        u16* dst = &xfT[(size_t)r * 65536 + i0 + io];
        *(ushort4*)&dst[0] = z4;
        *(ushort4*)&dst[4] = z4;
    }
}

// ---------------------------------------------------------------------------
// Fused conversion + S-partial GEMM. Wave-balanced MFMA: 13 (nt,ct) pairs
// per wave (q=w+p -> nt=q&3, ctloc=q>>2; switch(w) keeps indices static).
// ---------------------------------------------------------------------------
__global__ __launch_bounds__(256, 3) void k_bigS(const float* __restrict__ Q,
                                                 const u16* __restrict__ xfT,
                                                 u16* __restrict__ Qbf,
                                                 float* __restrict__ S_part,
                                                 float* __restrict__ csPart) {
    __shared__ __align__(16) u16 Bt[2][208 * 32];
    __shared__ __align__(16) u16 At[64 * 34];
    const int bid = blockIdx.x;
    const int xcd = bid & 7, jb = bid >> 3;
    const int nt_b = jb & 31;
    const int ks_b = ((jb >> 5) << 3) + xcd;
    const int n0 = nt_b * 64;
    const size_t i0 = (size_t)ks_b * 2048;
    const int t = threadIdx.x, w = t >> 6, l = t & 63;
    const int ctlo = (w * 13) >> 2;
    const int lrowB = l >> 2;
    const int scolB = (((l & 3) ^ ((l >> 3) & 3)) << 3);
    const int nq = t & 15;
    const int kp = t >> 4;

    f32x4 acc[13];
#pragma unroll
    for (int a = 0; a < 13; ++a) acc[a] = (f32x4){0.f, 0.f, 0.f, 0.f};
    float csum[4] = {0.f, 0.f, 0.f, 0.f};

    float4 aq0, ar0, aq1, ar1;

#define ISSUE_B(PAR, STEP)                                                      \
    {                                                                           \
        const size_t kc = i0 + (size_t)(STEP) * 32 + scolB;                     \
        for (int s = w; s < 13; s += 4)                                         \
            gload16(&xfT[(size_t)(s * 16 + lrowB) * 65536 + kc],                \
                    &Bt[PAR][s * 512]);                                         \
    }

#define LOAD_A(AQ, AR, STEP)                                                    \
    {                                                                           \
        const float* qp = &Q[(i0 + (size_t)(STEP) * 32 + kp * 2) * 2048         \
                             + n0 + nq * 4];                                    \
        AQ = *(const float4*)qp;                                                \
        AR = *(const float4*)(qp + 2048);                                       \
    }

#define WRITE_A(AQ, AR, STEP)                                                   \
    {                                                                           \
        const float* ca = (const float*)&AQ;                                    \
        const float* cb = (const float*)&AR;                                    \
        ushort4 s0, s1;                                                         \
        u16* q0 = (u16*)&s0; u16* q1 = (u16*)&s1;                               \
        _Pragma("unroll")                                                       \
        for (int jj = 0; jj < 4; ++jj) {                                        \
            const int n_ = nq * 4 + jj;                                         \
            ushort2 p2;                                                         \
            p2.x = f2bf(ca[jj]); p2.y = f2bf(cb[jj]);                           \
            *(ushort2*)&At[n_ * 34 + ((n_ & 1) << 1) + kp * 2] = p2;            \
            csum[jj] += ca[jj] + cb[jj];                                        \
            q0[jj] = p2.x; q1[jj] = p2.y;                                       \
        }                                                                       \
        const size_t r0 = i0 + (size_t)(STEP) * 32 + kp * 2;                    \
        *(ushort4*)&Qbf[r0 * 2048 + n0 + nq * 4] = s0;                          \
        *(ushort4*)&Qbf[(r0 + 1) * 2048 + n0 + nq * 4] = s1;                    \
    }

#define MFMA13(W)                                                               \
    {                                                                           \
        _Pragma("unroll")                                                       \
        for (int p = 0; p < 13; ++p) {                                          \
            const int q = (W) + p;                                              \
            acc[p] = __builtin_amdgcn_mfma_f32_16x16x32_bf16(                   \
                af[q & 3].v, bf[q >> 2].v, acc[p], 0, 0, 0);                    \
        }                                                                       \
    }

#define MFMA_PHASE(PAR)                                                         \
    {                                                                           \
        const u16* Bb = Bt[PAR];                                                \
        const int g = l >> 4;                                                   \
        FragA af[4];                                                            \
        _Pragma("unroll")                                                       \
        for (int nt = 0; nt < 4; ++nt) {                                        \
            const int r = nt * 16 + (l & 15);                                   \
            const int ab = r * 34 + ((r & 1) << 1) + g * 8;                     \
            af[nt].u2[0] = *(const uint2*)&At[ab];                              \
            af[nt].u2[1] = *(const uint2*)&At[ab + 4];                          \
        }                                                                       \
        Frag bf[4];                                                             \
        _Pragma("unroll")                                                       \
        for (int j = 0; j < 4; ++j) {                                           \
            const int rb = (ctlo + j) * 16 + (l & 15);                          \
            bf[j].v = *(const short8*)&Bb[rb * 32 + ((g ^ ((rb >> 1) & 3)) << 3)]; \
        }                                                                       \
        switch (w) {                                                            \
            case 0: MFMA13(0); break;                                           \
            case 1: MFMA13(1); break;                                           \
            case 2: MFMA13(2); break;                                           \
            default: MFMA13(3); break;                                          \
        }                                                                       \
    }

#define STEPBODY(STEP, PAR, NPAR, CQ, CR, COND)                                 \
    {                                                                           \
        if (COND) ISSUE_B(NPAR, (STEP) + 1);                                    \
        WRITE_A(CQ, CR, STEP);                                                  \
        {                                                                       \
            const int nst = ((STEP) + 2 > 63) ? 63 : (STEP) + 2;                \
            LOAD_A(CQ, CR, nst);                                                \
        }                                                                       \
        asm volatile("s_waitcnt lgkmcnt(0)" ::: "memory");                      \
        __builtin_amdgcn_s_barrier();                                           \
        if (COND) {                                                             \
            if (w == 0) asm volatile("s_waitcnt vmcnt(12)" ::: "memory");       \
            else        asm volatile("s_waitcnt vmcnt(11)" ::: "memory");       \
        } else {                                                                \
            asm volatile("s_waitcnt vmcnt(0)" ::: "memory");                    \
        }                                                                       \
        MFMA_PHASE(PAR);                                                        \
        __builtin_amdgcn_s_barrier();                                           \
    }

    ISSUE_B(0, 0);
    LOAD_A(aq0, ar0, 0);
    LOAD_A(aq1, ar1, 1);

    for (int s2 = 0; s2 < 32; ++s2) {
        STEPBODY(s2 * 2,     0, 1, aq0, ar0, true);
        STEPBODY(s2 * 2 + 1, 1, 0, aq1, ar1, (s2 < 31));
    }
#undef STEPBODY
#undef MFMA_PHASE
#undef MFMA13
#undef WRITE_A
#undef LOAD_A
#undef ISSUE_B

    __syncthreads();
    float* csF = (float*)At;
#pragma unroll
    for (int jj = 0; jj < 4; ++jj)
        csF[kp * 64 + nq * 4 + jj] = csum[jj];
    __syncthreads();
    if (t < 64) {
        float s = 0.f;
#pragma unroll
        for (int g2 = 0; g2 < 16; ++g2) s += csF[g2 * 64 + t];
        csPart[(size_t)ks_b * 2048 + n0 + t] = s;
    }
    float* Sp = S_part + (size_t)ks_b * 409600;
#pragma unroll
    for (int p = 0; p < 13; ++p) {
        const int q = w + p;
        const int cc = (ctlo + (q >> 2)) * 16 + (l & 15);
        if (cc < 200) {
            const int nbase = n0 + (q & 3) * 16 + ((l >> 4) << 2);
#pragma unroll
            for (int r = 0; r < 4; ++r)
                Sp[(size_t)(nbase + r) * 200 + cc] = acc[p][r];
        }
    }
}

// xn = BN * (sum S_part) / (sum csPart)
__global__ void k_redS(const float* __restrict__ S_part, const float* __restrict__ csPart,
                       float* __restrict__ xn) {
    int i = blockIdx.x * 256 + threadIdx.x;
    if (i >= N * C) return;
    int n = i / C;
    float s = 0.f, csn = 0.f;
#pragma unroll 8
    for (int p = 0; p < 32; ++p) s += S_part[(size_t)p * 409600 + i];
#pragma unroll 8
    for (int p = 0; p < 32; ++p) csn += csPart[(size_t)p * 2048 + n];
    xn[i] = BNF * s / csn;
}

// ---------------------------------------------------------------------------
// Merged: z<4 -> GAT Wh head z (+f1/f2 epilogue); z==4 -> GCN mm1 (BNF^2).
// ---------------------------------------------------------------------------
__global__ __launch_bounds__(256) void k_wh5(const float* __restrict__ xn,
                                             const float* __restrict__ gatW,
                                             const float* __restrict__ gata,
                                             const float* __restrict__ g1aW,
                                             float* __restrict__ WhB,
                                             float* __restrict__ f1,
                                             float* __restrict__ f2,
                                             float* __restrict__ hbuf) {
    __shared__ float ldsA[32][33];
    __shared__ float ldsW[32][128];
    __shared__ float ldsWh[32][129];
    const int rt = blockIdx.x * 32;
    const int z  = blockIdx.y;
    const bool gat = z < 4;
    const float* Wp = gat ? gatW + (size_t)z * 25600 : g1aW;
    const int t = threadIdx.x;
    const int col = t & 127, rg = t >> 7;
    float acc[16];
#pragma unroll
    for (int r = 0; r < 16; ++r) acc[r] = 0.f;

    for (int k0 = 0; k0 < 200; k0 += 32) {
        for (int idx = t; idx < 32 * 32; idx += 256) {
            int r = idx >> 5, kk = idx & 31;
            int k = k0 + kk;
            ldsA[r][kk] = (k < 200) ? xn[(size_t)(rt + r) * 200 + k] : 0.f;
        }
        for (int idx = t; idx < 32 * 128; idx += 256) {
            int kk = idx >> 7, c = idx & 127;
            int k = k0 + kk;
            ldsW[kk][c] = (k < 200) ? Wp[(size_t)k * 128 + c] : 0.f;
        }
        __syncthreads();
#pragma unroll 8
        for (int kk = 0; kk < 32; ++kk) {
            float wv = ldsW[kk][col];
#pragma unroll
            for (int r = 0; r < 16; ++r) acc[r] += ldsA[rg * 16 + r][kk] * wv;
        }
        __syncthreads();
    }
    if (gat) {
#pragma unroll
        for (int r = 0; r < 16; ++r) {
            ldsWh[rg * 16 + r][col] = acc[r];
            WhB[(size_t)(rt + rg * 16 + r) * 512 + z * 128 + col] = acc[r];
        }
        __syncthreads();
        int row = t >> 3, p = t & 7;
        const float* a = gata + z * 256;
        float s1 = 0.f, s2 = 0.f;
#pragma unroll
        for (int j = 0; j < 16; ++j) {
            int c = p * 16 + j;
            float v = ldsWh[row][c];
            s1 += v * a[c]; s2 += v * a[128 + c];
        }
        s1 += __shfl_xor(s1, 1); s1 += __shfl_xor(s1, 2); s1 += __shfl_xor(s1, 4);
        s2 += __shfl_xor(s2, 1); s2 += __shfl_xor(s2, 2); s2 += __shfl_xor(s2, 4);
        if (p == 0) { f1[z * N + rt + row] = s1; f2[z * N + rt + row] = s2; }
    } else {
        const float sc = BNF * BNF;
#pragma unroll
        for (int r = 0; r < 16; ++r)
            hbuf[(size_t)(rt + rg * 16 + r) * 128 + col] = sc * acc[r];
    }
}

// ---------------------------------------------------------------------------
// Merged: vb<1024 -> spmm1 (W=128); else -> att_head (2 per block).
// ---------------------------------------------------------------------------
__global__ void k_s1ah(const float* __restrict__ hbuf, const int* __restrict__ deg,
                       const int* __restrict__ idxs, const float* __restrict__ g1ab,
                       float* __restrict__ zbuf, const float* __restrict__ WhB,
                       const float* __restrict__ f1, const float* __restrict__ f2,
                       float* __restrict__ hcat) {
    __shared__ float eW[256];
    const int vb = blockIdx.x;
    const int t = threadIdx.x;
    if (vb < 1024) {
        const int n = vb * 2 + (t >> 7), k = t & 127;
        const int d = deg[n];
        const int* row = idxs + (size_t)n * MAXDEG;
        float a = 0.f;
        for (int j = 0; j < d; ++j) a += hbuf[(size_t)row[j] * 128 + k];
        float v = a + g1ab[k];
        v = v >= 0.f ? v : 0.01f * v;
        zbuf[(size_t)n * 128 + k] = v;
    } else {
        const int va = vb - 1024;
        const int half = t >> 7, k = t & 127;
        const int u = va * 2 + half;
        const int h = u >> 11, n = u & 2047;
        const int d = deg[n];
        const int* row = idxs + (size_t)n * MAXDEG;
        const float f1v = f1[h * N + n];
        const float* f2h = f2 + h * N;
        float* e = eW + half * 128;
        if (k < d) {
            float ev = f1v + f2h[row[k]];
            e[k] = ev >= 0.f ? ev : 0.2f * ev;
        }
        __syncthreads();
        float mx = -1e30f;
        for (int j = 0; j < d; ++j) mx = fmaxf(mx, e[j]);
        __syncthreads();
        if (k < d) e[k] = __expf(e[k] - mx);
        __syncthreads();
        float ssum = 0.f, acc = 0.f;
        for (int j = 0; j < d; ++j) ssum += e[j];
        for (int j = 0; j < d; ++j)
            acc += e[j] * WhB[(size_t)row[j] * 512 + h * 128 + k];
        float v = acc / ssum;
        v = v > 0.f ? v : __expf(v) - 1.f;
        hcat[(size_t)n * 512 + h * 128 + k] = v;
    }
}

// ---------------------------------------------------------------------------
// Merged: vb<256 -> mm g1b (zbuf@g1bW -> hbuf200); else -> mmO (+f1o/f2o).
// ---------------------------------------------------------------------------
__global__ __launch_bounds__(256) void k_g1bO(const float* __restrict__ zbuf,
                                              const float* __restrict__ g1bW,
                                              float* __restrict__ hbuf,
                                              const float* __restrict__ hcat,
                                              const float* __restrict__ outW,
                                              const float* __restrict__ outa,
                                              float* __restrict__ WhO,
                                              float* __restrict__ f1o,
                                              float* __restrict__ f2o) {
    __shared__ float ldsA[32][33];
    __shared__ float ldsW[32][65];
    const int vb = blockIdx.x;
    const int t = threadIdx.x;
    const int lane = t & 63, wg = t >> 6;
    float acc[8];
#pragma unroll
    for (int r = 0; r < 8; ++r) acc[r] = 0.f;

    if (vb < 256) {
        const int rt = (vb & 63) * 32, ct = (vb >> 6) * 64;
        for (int k0 = 0; k0 < 128; k0 += 32) {
            for (int idx = t; idx < 1024; idx += 256) {
                int r = idx >> 5, kk = idx & 31;
                ldsA[r][kk] = zbuf[(size_t)(rt + r) * 128 + k0 + kk];
            }
            for (int idx = t; idx < 2048; idx += 256) {
                int kk = idx >> 6, c = idx & 63;
                int cg = ct + c;
                ldsW[kk][c] = (cg < 200) ? g1bW[(size_t)(k0 + kk) * 200 + cg] : 0.f;
            }
            __syncthreads();
#pragma unroll 8
            for (int kk = 0; kk < 32; ++kk) {
                float wv = ldsW[kk][lane];
#pragma unroll
                for (int r = 0; r < 8; ++r) acc[r] += ldsA[wg * 8 + r][kk] * wv;
            }
            __syncthreads();
        }
        int cg = ct + lane;
        if (cg < 200) {
#pragma unroll
            for (int r = 0; r < 8; ++r)
                hbuf[(size_t)(rt + wg * 8 + r) * 200 + cg] = BNF * acc[r];
        }
    } else {
        const int rt = (vb - 256) * 32;
        for (int k0 = 0; k0 < 512; k0 += 32) {
            for (int idx = t; idx < 1024; idx += 256) {
                int r = idx >> 5, kk = idx & 31;
                ldsA[r][kk] = hcat[(size_t)(rt + r) * 512 + k0 + kk];
            }
            for (int idx = t; idx < 2048; idx += 256) {
                int kk = idx >> 6, c = idx & 63;
                ldsW[kk][c] = outW[(size_t)(k0 + kk) * 64 + c];
            }
            __syncthreads();
#pragma unroll 8
            for (int kk = 0; kk < 32; ++kk) {
                float wv = ldsW[kk][lane];
#pragma unroll
                for (int r = 0; r < 8; ++r) acc[r] += ldsA[wg * 8 + r][kk] * wv;
            }
            __syncthreads();
        }
#pragma unroll
        for (int r = 0; r < 8; ++r)
            WhO[(size_t)(rt + wg * 8 + r) * 64 + lane] = acc[r];
#pragma unroll
        for (int r = 0; r < 8; ++r) {
            float v1 = acc[r] * outa[lane];
            float v2 = acc[r] * outa[64 + lane];
#pragma unroll
            for (int off = 32; off; off >>= 1) {
                v1 += __shfl_down(v1, off);
                v2 += __shfl_down(v2, off);
            }
            if (lane == 0) { f1o[rt + wg * 8 + r] = v1; f2o[rt + wg * 8 + r] = v2; }
        }
    }
}

// ---------------------------------------------------------------------------
// Fused spmm2 + mm g2a: 16 rows/block (grid 128). xg2 kept in LDS.
// xg2 = lrelu(BNF*(gather(hbuf200)+g1bb)) + BNF*xn ; out = BNF * xg2 @ g2aW.
// ---------------------------------------------------------------------------
__global__ __launch_bounds__(256) void k_s2g2a(const float* __restrict__ hbuf,
                                               const int* __restrict__ deg,
                                               const int* __restrict__ idxs,
                                               const float* __restrict__ g1bb,
                                               const float* __restrict__ xn,
                                               const float* __restrict__ g2aW,
                                               float* __restrict__ outp) {
    __shared__ float X[16][204];
    __shared__ float ldsW[32][128];
    const int rt = blockIdx.x * 16;
    const int t = threadIdx.x;
    {
        const int row = t >> 4, tc = t & 15;
        const int n = rt + row;
        const int d = deg[n];
        const int* rp = idxs + (size_t)n * MAXDEG;
        float a[13];
#pragma unroll
        for (int c = 0; c < 13; ++c) a[c] = 0.f;
        for (int j = 0; j < d; ++j) {
            const float* hr = hbuf + (size_t)rp[j] * 200;
#pragma unroll
            for (int c = 0; c < 13; ++c) {
                int col = tc + 16 * c;
                if (col < 200) a[c] += hr[col];
            }
        }
#pragma unroll
        for (int c = 0; c < 13; ++c) {
            int col = tc + 16 * c;
            if (col < 200) {
                float v = BNF * (a[c] + g1bb[col]);
                v = v >= 0.f ? v : 0.01f * v;
                v += BNF * xn[(size_t)n * 200 + col];
                X[row][col] = v;
            }
        }
    }
    __syncthreads();
    const int col = t & 127, rg = t >> 7;
    float acc[8];
#pragma unroll
    for (int r = 0; r < 8; ++r) acc[r] = 0.f;
    for (int k0 = 0; k0 < 200; k0 += 32) {
        for (int idx = t; idx < 4096; idx += 256) {
            int kk = idx >> 7, c = idx & 127;
            int k = k0 + kk;
            ldsW[kk][c] = (k < 200) ? g2aW[(size_t)k * 128 + c] : 0.f;
        }
        __syncthreads();
#pragma unroll 8
        for (int kk = 0; kk < 32; ++kk) {
            if (k0 + kk < 200) {
                float wv = ldsW[kk][col];
#pragma unroll
                for (int r = 0; r < 8; ++r) acc[r] += X[rg * 8 + r][k0 + kk] * wv;
            }
        }
        __syncthreads();
    }
#pragma unroll
    for (int r = 0; r < 8; ++r)
        outp[(size_t)(rt + rg * 8 + r) * 128 + col] = BNF * acc[r];
}

// ---------------------------------------------------------------------------
// Fused spmm3 + mm g2b: 16 rows/block (grid 128). z kept in LDS.
// z = lrelu(gather(in128)+g2ab) ; out64 = BNF * z @ g2bW.
// ---------------------------------------------------------------------------
__global__ __launch_bounds__(256) void k_s3g2b(const float* __restrict__ inp,
                                               const int* __restrict__ deg,
                                               const int* __restrict__ idxs,
                                               const float* __restrict__ g2ab,
                                               const float* __restrict__ g2bW,
                                               float* __restrict__ outp) {
    __shared__ float Z[16][132];
    __shared__ float ldsW[32][65];
    const int rt = blockIdx.x * 16;
    const int t = threadIdx.x;
    {
        const int row = t >> 4, tc = t & 15;
        const int n = rt + row;
        const int d = deg[n];
        const int* rp = idxs + (size_t)n * MAXDEG;
        float a[8];
#pragma unroll
        for (int c = 0; c < 8; ++c) a[c] = 0.f;
        for (int j = 0; j < d; ++j) {
            const float* hr = inp + (size_t)rp[j] * 128;
#pragma unroll
            for (int c = 0; c < 8; ++c) a[c] += hr[tc + 16 * c];
        }
#pragma unroll
        for (int c = 0; c < 8; ++c) {
            int col = tc + 16 * c;
            float v = a[c] + g2ab[col];
            Z[row][col] = v >= 0.f ? v : 0.01f * v;
        }
    }
    __syncthreads();
    const int lane = t & 63, wg = t >> 6;
    float acc[4];
#pragma unroll
    for (int r = 0; r < 4; ++r) acc[r] = 0.f;
    for (int k0 = 0; k0 < 128; k0 += 32) {
        for (int idx = t; idx < 2048; idx += 256) {
            int kk = idx >> 6, c = idx & 63;
            ldsW[kk][c] = g2bW[(size_t)(k0 + kk) * 64 + c];
        }
        __syncthreads();
#pragma unroll 8
        for (int kk = 0; kk < 32; ++kk) {
            float wv = ldsW[kk][lane];
#pragma unroll
            for (int r = 0; r < 4; ++r) acc[r] += Z[wg * 4 + r][k0 + kk] * wv;
        }
        __syncthreads();
    }
#pragma unroll
    for (int r = 0; r < 4; ++r)
        outp[(size_t)(rt + wg * 4 + r) * 64 + lane] = BNF * acc[r];
}

// ---------------------------------------------------------------------------
// Fused spmm4 + att_out + fusion: 4 nodes/block (grid 512). GCNx in register.
// ---------------------------------------------------------------------------
__global__ void k_s4ao(const float* __restrict__ h64, const int* __restrict__ deg,
                       const int* __restrict__ idxs, const float* __restrict__ g2bb,
                       const float* __restrict__ WhO, const float* __restrict__ f1o,
                       const float* __restrict__ f2o,
                       const float* __restrict__ Wf, const float* __restrict__ bfp,
                       const float* __restrict__ cw, const float* __restrict__ cb,
                       u16* __restrict__ yT) {
    __shared__ float eW[4][MAXDEG];
    const int sub = threadIdx.x >> 6, k = threadIdx.x & 63;
    const int n = blockIdx.x * 4 + sub;
    const int d = deg[n];
    const int* row = idxs + (size_t)n * MAXDEG;
    // spmm4: GCNx value in register
    float a = 0.f;
    for (int j = 0; j < d; ++j) a += h64[(size_t)row[j] * 64 + k];
    float g = a + g2bb[k];
    g = g >= 0.f ? g : 0.01f * g;
    g *= BNF;
    // att_out
    const float f1v = f1o[n];
    float* e = eW[sub];
    for (int j = k; j < d; j += 64) {
        float ev = f1v + f2o[row[j]];
        e[j] = ev >= 0.f ? ev : 0.2f * ev;
    }
    __syncthreads();
    float mx = -1e30f;
    for (int j = 0; j < d; ++j) mx = fmaxf(mx, e[j]);
    __syncthreads();
    for (int j = k; j < d; j += 64) e[j] = __expf(e[j] - mx);
    __syncthreads();
    float ssum = 0.f, acc = 0.f;
    for (int j = 0; j < d; ++j) ssum += e[j];
    for (int j = 0; j < d; ++j) acc += e[j] * WhO[(size_t)row[j] * 64 + k];
    float v = acc / ssum;
    v = v > 0.f ? v : __expf(v) - 1.f;   // elu
    v *= BNF;
    float gat = v >= 0.f ? v : 0.01f * v;
    float mn = fminf(g, gat), mxv = fmaxf(g, gat);
    float avg = g * Wf[k] + bfp[k] + gat * Wf[64 + k] + bfp[64 + k];
    float base = g + gat;
    float yv = cw[0] * (mn + base) + cw[1] * (mxv + base) + cw[2] * (avg + base) + cb[0];
    yv *= BNF;
    yv = yv >= 0.f ? yv : 0.2f * yv;
    yT[k * 2048 + n] = f2bf(yv);
}

// ---------------------------------------------------------------------------
// out[i,f] = sum_n Qbf[i,n]*yT[f,n] (round-10 proven, unchanged).
// ---------------------------------------------------------------------------
__global__ __launch_bounds__(256, 2) void k_final(const u16* __restrict__ Qbf,
                                                  const u16* __restrict__ yT,
                                                  float* __restrict__ out) {
    __shared__ __align__(16) u16 Aq[3][128 * 64];
    __shared__ __align__(16) u16 By[3][64 * 64];
    const int i0 = blockIdx.x * 128;
    const int t = threadIdx.x, w = t >> 6, l = t & 63;
    const int lrow = l >> 3;
    const int scol = (((l & 7) ^ ((l >> 3) & 7)) << 3);
    f32x4 acc[2][4];
#pragma unroll
    for (int a = 0; a < 2; ++a)
#pragma unroll
        for (int b = 0; b < 4; ++b) acc[a][b] = (f32x4){0.f, 0.f, 0.f, 0.f};

#define STAGE_F(buf, step)                                                          \
    {                                                                               \
        const size_t kc = (size_t)(step) * 64 + scol;                               \
        for (int s = w; s < 16; s += 4)                                             \
            gload16(&Qbf[(size_t)(i0 + s * 8 + lrow) * 2048 + kc],                  \
                    &Aq[buf][s * 512]);                                             \
        for (int s = w; s < 8; s += 4)                                              \
            gload16(&yT[(size_t)(s * 8 + lrow) * 2048 + kc],                        \
                    &By[buf][s * 512]);                                             \
    }

    STAGE_F(0, 0);
    STAGE_F(1, 1);
    for (int step = 0; step < 32; ++step) {
        const int cur = step % 3;
        if (step + 2 < 32) STAGE_F((step + 2) % 3, step + 2);
        if (step + 2 < 32)      asm volatile("s_waitcnt vmcnt(12)" ::: "memory");
        else if (step + 1 < 32) asm volatile("s_waitcnt vmcnt(6)"  ::: "memory");
        else                    asm volatile("s_waitcnt vmcnt(0)"  ::: "memory");
        __builtin_amdgcn_s_barrier();

        const u16* Ab = Aq[cur];
        const u16* Bb = By[cur];
#pragma unroll
        for (int sub = 0; sub < 2; ++sub) {
            const int c8 = sub * 4 + (l >> 4);
            Frag a[2];
#pragma unroll
            for (int it = 0; it < 2; ++it) {
                const int r = w * 32 + it * 16 + (l & 15);
                a[it].v = *(const short8*)&Ab[r * 64 + ((c8 ^ (r & 7)) << 3)];
            }
#pragma unroll
            for (int ft = 0; ft < 4; ++ft) {
                const int rb = ft * 16 + (l & 15);
                Frag b;
                b.v = *(const short8*)&Bb[rb * 64 + ((c8 ^ (rb & 7)) << 3)];
#pragma unroll
                for (int it = 0; it < 2; ++it)
                    acc[it][ft] = __builtin_amdgcn_mfma_f32_16x16x32_bf16(
                        a[it].v, b.v, acc[it][ft], 0, 0, 0);
            }
        }
        asm volatile("s_waitcnt lgkmcnt(0)" ::: "memory");
        __builtin_amdgcn_s_barrier();
    }
#undef STAGE_F
#pragma unroll
    for (int it = 0; it < 2; ++it)
#pragma unroll
        for (int ft = 0; ft < 4; ++ft) {
            const int i = i0 + w * 32 + it * 16 + ((l >> 4) << 2);
            const int f = ft * 16 + (l & 15);
#pragma unroll
            for (int r = 0; r < 4; ++r)
                out[(size_t)(i + r) * 64 + f] = acc[it][ft][r];
        }
}

extern "C" void kernel_launch(void* const* d_in, const int* in_sizes, int n_in,
                              void* d_out, int out_size, void* d_ws, size_t ws_size,
                              hipStream_t stream) {
    const float* x     = (const float*)d_in[0];
    const float* adj   = (const float*)d_in[1];
    const float* Q     = (const float*)d_in[2];
    const float* g1aW  = (const float*)d_in[3];
    const float* g1ab  = (const float*)d_in[4];
    const float* g1bW  = (const float*)d_in[5];
    const float* g1bb  = (const float*)d_in[6];
    const float* g2aW  = (const float*)d_in[7];
    const float* g2ab  = (const float*)d_in[8];
    const float* g2bW  = (const float*)d_in[9];
    const float* g2bb  = (const float*)d_in[10];
    const float* gatW  = (const float*)d_in[11];
    const float* gata  = (const float*)d_in[12];
    const float* outW  = (const float*)d_in[13];
    const float* outa  = (const float*)d_in[14];
    const float* Wf    = (const float*)d_in[15];
    const float* bfp   = (const float*)d_in[16];
    const float* convw = (const float*)d_in[17];
    const float* convb = (const float*)d_in[18];

    float* ws   = (float*)d_ws;
    float* xn   = ws + 411648;
    float* hbuf = ws + 1640448;
    float* zbuf = ws + 2050048;
    float* WhO  = ws + 2312192;
    float* f1   = ws + 2836480;
    float* f2   = ws + 2844672;
    float* f1o  = ws + 2852864;
    float* f2o  = ws + 2854912;
    int*   deg  = (int*)(ws + 2856960);
    int*   idxs = (int*)(ws + 2859008);   // ends 3055616
    u16*   yT   = (u16*)(ws + 3300000);   // own slot (s4ao reads hbuf64 while writing yT)
    float* csPart = ws + 3600000;
    float* S_part = ws + 4200000;         // 52 MB
    u16*   Qbf    = (u16*)(ws + 71308864);
    u16*   xfT    = (u16*)(ws + 138417728);

    float* out  = (float*)d_out;
    float* WhB  = out;             // 2048*512 scratch inside d_out
    float* hcat = out + 1048576;   // 2048*512 scratch inside d_out

    // ---- conversion (+CSR co-scheduled) + big S GEMM ----
    k_convX<<<1024, 256, 0, stream>>>(x, xfT, adj, deg, idxs);
    k_bigS<<<1024, 256, 0, stream>>>(Q, xfT, Qbf, S_part, csPart);
    k_redS<<<1600, 256, 0, stream>>>(S_part, csPart, xn);

    // ---- GNN mid-section: 6 launches ----
    k_wh5<<<dim3(64, 5), 256, 0, stream>>>(xn, gatW, gata, g1aW, WhB, f1, f2, hbuf);
    k_s1ah<<<5120, 256, 0, stream>>>(hbuf, deg, idxs, g1ab, zbuf, WhB, f1, f2, hcat);
    k_g1bO<<<320, 256, 0, stream>>>(zbuf, g1bW, hbuf, hcat, outW, outa, WhO, f1o, f2o);
    k_s2g2a<<<128, 256, 0, stream>>>(hbuf, deg, idxs, g1bb, xn, g2aW, zbuf);
    k_s3g2b<<<128, 256, 0, stream>>>(zbuf, deg, idxs, g2ab, g2bW, hbuf);
    k_s4ao<<<512, 256, 0, stream>>>(hbuf, deg, idxs, g2bb, WhO, f1o, f2o,
                                    Wf, bfp, convw, convb, yT);

    // ---- final projection (overwrites WhB/hcat scratch in d_out) ----
    k_final<<<512, 256, 0, stream>>>(Qbf, yT, out);
}

// Round 15
// 670.271 us; speedup vs baseline: 1.3712x; 1.3712x over previous
//
#include <hip/hip_runtime.h>
#include <math.h>

#define BNF 0.9999950000374997f

constexpr int N    = 2048;
constexpr int C    = 200;
constexpr int HW   = 65536;
constexpr int MAXDEG = 96;

typedef unsigned short u16;
typedef __attribute__((ext_vector_type(8))) short short8;
typedef __attribute__((ext_vector_type(4))) float f32x4;

union Frag  { short8 v; ushort4 h[2]; };
union FragA { short8 v; uint2 u2[2]; };

__device__ inline u16 f2bf(float x) {
    unsigned int u = __float_as_uint(x);
    unsigned int r = (u + 0x7fffu + ((u >> 16) & 1u)) >> 16;
    return (u16)r;
}

__device__ __forceinline__ void gload16(const void* g, void* l) {
    __builtin_amdgcn_global_load_lds(
        (const __attribute__((address_space(1))) unsigned int*)g,
        (__attribute__((address_space(3))) unsigned int*)l, 16, 0, 0);
}

// ---------------------------------------------------------------------------
// blocks 0..511: xf -> xfT [208][65536] bf16 (rows 200..207 zeroed)
// blocks 512..1023: CSR build
// ---------------------------------------------------------------------------
__global__ __launch_bounds__(256) void k_convX(const float* __restrict__ xf,
                                               u16* __restrict__ xfT,
                                               const float* __restrict__ adj,
                                               int* __restrict__ deg,
                                               int* __restrict__ idxs) {
    const int t = threadIdx.x;
    if (blockIdx.x >= 512) {
        int w = t >> 6, lane = t & 63;
        int n = (blockIdx.x - 512) * 4 + w;
        const float* row = adj + (size_t)n * N;
        int base = 0;
        for (int c = 0; c < N; c += 64) {
            float v = row[c + lane];
            bool p = v > 0.f;
            unsigned long long m = __ballot(p);
            int pos = __popcll(m & ((1ull << lane) - 1ull));
            if (p && (base + pos) < MAXDEG)
                idxs[(size_t)n * MAXDEG + base + pos] = c + lane;
            base += __popcll(m);
        }
        if (lane == 0) deg[n] = base < MAXDEG ? base : MAXDEG;
        return;
    }
    __shared__ __align__(16) u16 T2[200][140];
    const int i0 = blockIdx.x * 128;
    for (int p = 0; p < 25; ++p) {
        int idx = p * 256 + t;
        int il = idx / 50, cq = idx % 50;
        float4 v = *(const float4*)&xf[(size_t)(i0 + il) * 200 + cq * 4];
        T2[cq * 4 + 0][il] = f2bf(v.x);
        T2[cq * 4 + 1][il] = f2bf(v.y);
        T2[cq * 4 + 2][il] = f2bf(v.z);
        T2[cq * 4 + 3][il] = f2bf(v.w);
    }
    __syncthreads();
    for (int p = 0; p < 13; ++p) {
        int c = p * 16 + (t >> 4);
        if (c < 200) {
            int io = (t & 15) * 8;
            u16* dst = &xfT[(size_t)c * 65536 + i0 + io];
            *(ushort4*)&dst[0] = *(const ushort4*)&T2[c][io];
            *(ushort4*)&dst[4] = *(const ushort4*)&T2[c][io + 4];
        }
    }
    ushort4 z4 = {0, 0, 0, 0};
    for (int idx = t; idx < 8 * 16; idx += 256) {
        int r = 200 + (idx >> 4), io = (idx & 15) * 8;
        u16* dst = &xfT[(size_t)r * 65536 + i0 + io];
        *(ushort4*)&dst[0] = z4;
        *(ushort4*)&dst[4] = z4;
    }
}

// ---------------------------------------------------------------------------
// Fused conversion + S-partial GEMM (round-10/13 proven version, reverted:
// the round-14 switch(w)-balanced variant doubled k_bigS time via code-size
// explosion — 104 static MFMAs/iter thrashed I-cache).
// ---------------------------------------------------------------------------
__global__ __launch_bounds__(256, 3) void k_bigS(const float* __restrict__ Q,
                                                 const u16* __restrict__ xfT,
                                                 u16* __restrict__ Qbf,
                                                 float* __restrict__ S_part,
                                                 float* __restrict__ csPart) {
    __shared__ __align__(16) u16 Bt[2][208 * 32];
    __shared__ __align__(16) u16 At[64 * 34];
    const int bid = blockIdx.x;
    const int xcd = bid & 7, jb = bid >> 3;
    const int nt_b = jb & 31;
    const int ks_b = ((jb >> 5) << 3) + xcd;
    const int n0 = nt_b * 64;
    const size_t i0 = (size_t)ks_b * 2048;
    const int t = threadIdx.x, w = t >> 6, l = t & 63;
    const int ct0 = (w == 0) ? 0 : (4 + (w - 1) * 3);
    const int nct = (w == 0) ? 4 : 3;
    const int lrowB = l >> 2;
    const int scolB = (((l & 3) ^ ((l >> 3) & 3)) << 3);
    const int nq = t & 15;
    const int kp = t >> 4;

    f32x4 acc[4][4];
#pragma unroll
    for (int a = 0; a < 4; ++a)
#pragma unroll
        for (int b = 0; b < 4; ++b) acc[a][b] = (f32x4){0.f, 0.f, 0.f, 0.f};
    float csum[4] = {0.f, 0.f, 0.f, 0.f};

    float4 aq0, ar0, aq1, ar1;

#define ISSUE_B(PAR, STEP)                                                      \
    {                                                                           \
        const size_t kc = i0 + (size_t)(STEP) * 32 + scolB;                     \
        for (int s = w; s < 13; s += 4)                                         \
            gload16(&xfT[(size_t)(s * 16 + lrowB) * 65536 + kc],                \
                    &Bt[PAR][s * 512]);                                         \
    }

#define LOAD_A(AQ, AR, STEP)                                                    \
    {                                                                           \
        const float* qp = &Q[(i0 + (size_t)(STEP) * 32 + kp * 2) * 2048         \
                             + n0 + nq * 4];                                    \
        AQ = *(const float4*)qp;                                                \
        AR = *(const float4*)(qp + 2048);                                       \
    }

#define WRITE_A(AQ, AR, STEP)                                                   \
    {                                                                           \
        const float* ca = (const float*)&AQ;                                    \
        const float* cb = (const float*)&AR;                                    \
        ushort4 s0, s1;                                                         \
        u16* q0 = (u16*)&s0; u16* q1 = (u16*)&s1;                               \
        _Pragma("unroll")                                                       \
        for (int jj = 0; jj < 4; ++jj) {                                        \
            const int n_ = nq * 4 + jj;                                         \
            ushort2 p2;                                                         \
            p2.x = f2bf(ca[jj]); p2.y = f2bf(cb[jj]);                           \
            *(ushort2*)&At[n_ * 34 + ((n_ & 1) << 1) + kp * 2] = p2;            \
            csum[jj] += ca[jj] + cb[jj];                                        \
            q0[jj] = p2.x; q1[jj] = p2.y;                                       \
        }                                                                       \
        const size_t r0 = i0 + (size_t)(STEP) * 32 + kp * 2;                    \
        *(ushort4*)&Qbf[r0 * 2048 + n0 + nq * 4] = s0;                          \
        *(ushort4*)&Qbf[(r0 + 1) * 2048 + n0 + nq * 4] = s1;                    \
    }

#define MFMA_PHASE(PAR)                                                         \
    {                                                                           \
        const u16* Bb = Bt[PAR];                                                \
        const int g = l >> 4;                                                   \
        FragA af[4];                                                            \
        _Pragma("unroll")                                                       \
        for (int nt = 0; nt < 4; ++nt) {                                        \
            const int r = nt * 16 + (l & 15);                                   \
            const int ab = r * 34 + ((r & 1) << 1) + g * 8;                     \
            af[nt].u2[0] = *(const uint2*)&At[ab];                              \
            af[nt].u2[1] = *(const uint2*)&At[ab + 4];                          \
        }                                                                       \
        _Pragma("unroll")                                                       \
        for (int c = 0; c < 4; ++c) {                                           \
            if (c < nct) {                                                      \
                const int rb = (ct0 + c) * 16 + (l & 15);                       \
                Frag bf;                                                        \
                bf.v = *(const short8*)&Bb[rb * 32 + ((g ^ ((rb >> 1) & 3)) << 3)]; \
                _Pragma("unroll")                                               \
                for (int nt = 0; nt < 4; ++nt)                                  \
                    acc[nt][c] = __builtin_amdgcn_mfma_f32_16x16x32_bf16(       \
                        af[nt].v, bf.v, acc[nt][c], 0, 0, 0);                   \
            }                                                                   \
        }                                                                       \
    }

#define STEPBODY(STEP, PAR, NPAR, CQ, CR, COND)                                 \
    {                                                                           \
        if (COND) ISSUE_B(NPAR, (STEP) + 1);                                    \
        WRITE_A(CQ, CR, STEP);                                                  \
        {                                                                       \
            const int nst = ((STEP) + 2 > 63) ? 63 : (STEP) + 2;                \
            LOAD_A(CQ, CR, nst);                                                \
        }                                                                       \
        asm volatile("s_waitcnt lgkmcnt(0)" ::: "memory");                      \
        __builtin_amdgcn_s_barrier();                                           \
        if (COND) {                                                             \
            if (w == 0) asm volatile("s_waitcnt vmcnt(12)" ::: "memory");       \
            else        asm volatile("s_waitcnt vmcnt(11)" ::: "memory");       \
        } else {                                                                \
            asm volatile("s_waitcnt vmcnt(0)" ::: "memory");                    \
        }                                                                       \
        MFMA_PHASE(PAR);                                                        \
        __builtin_amdgcn_s_barrier();                                           \
    }

    ISSUE_B(0, 0);
    LOAD_A(aq0, ar0, 0);
    LOAD_A(aq1, ar1, 1);

    for (int s2 = 0; s2 < 32; ++s2) {
        STEPBODY(s2 * 2,     0, 1, aq0, ar0, true);
        STEPBODY(s2 * 2 + 1, 1, 0, aq1, ar1, (s2 < 31));
    }
#undef STEPBODY
#undef MFMA_PHASE
#undef WRITE_A
#undef LOAD_A
#undef ISSUE_B

    __syncthreads();
    float* csF = (float*)At;
#pragma unroll
    for (int jj = 0; jj < 4; ++jj)
        csF[kp * 64 + nq * 4 + jj] = csum[jj];
    __syncthreads();
    if (t < 64) {
        float s = 0.f;
#pragma unroll
        for (int g2 = 0; g2 < 16; ++g2) s += csF[g2 * 64 + t];
        csPart[(size_t)ks_b * 2048 + n0 + t] = s;
    }
    float* Sp = S_part + (size_t)ks_b * 409600;
#pragma unroll
    for (int nt = 0; nt < 4; ++nt)
#pragma unroll
        for (int c = 0; c < 4; ++c) {
            if (c < nct) {
                const int cc = (ct0 + c) * 16 + (l & 15);
                if (cc < 200) {
                    const int nbase = n0 + nt * 16 + ((l >> 4) << 2);
#pragma unroll
                    for (int r = 0; r < 4; ++r)
                        Sp[(size_t)(nbase + r) * 200 + cc] = acc[nt][c][r];
                }
            }
        }
}

// xn = BN * (sum S_part) / (sum csPart)
__global__ void k_redS(const float* __restrict__ S_part, const float* __restrict__ csPart,
                       float* __restrict__ xn) {
    int i = blockIdx.x * 256 + threadIdx.x;
    if (i >= N * C) return;
    int n = i / C;
    float s = 0.f, csn = 0.f;
#pragma unroll 8
    for (int p = 0; p < 32; ++p) s += S_part[(size_t)p * 409600 + i];
#pragma unroll 8
    for (int p = 0; p < 32; ++p) csn += csPart[(size_t)p * 2048 + n];
    xn[i] = BNF * s / csn;
}

// ---------------------------------------------------------------------------
// Merged: z<4 -> GAT Wh head z (+f1/f2 epilogue); z==4 -> GCN mm1 (BNF^2).
// ---------------------------------------------------------------------------
__global__ __launch_bounds__(256) void k_wh5(const float* __restrict__ xn,
                                             const float* __restrict__ gatW,
                                             const float* __restrict__ gata,
                                             const float* __restrict__ g1aW,
                                             float* __restrict__ WhB,
                                             float* __restrict__ f1,
                                             float* __restrict__ f2,
                                             float* __restrict__ hbuf) {
    __shared__ float ldsA[32][33];
    __shared__ float ldsW[32][128];
    __shared__ float ldsWh[32][129];
    const int rt = blockIdx.x * 32;
    const int z  = blockIdx.y;
    const bool gat = z < 4;
    const float* Wp = gat ? gatW + (size_t)z * 25600 : g1aW;
    const int t = threadIdx.x;
    const int col = t & 127, rg = t >> 7;
    float acc[16];
#pragma unroll
    for (int r = 0; r < 16; ++r) acc[r] = 0.f;

    for (int k0 = 0; k0 < 200; k0 += 32) {
        for (int idx = t; idx < 32 * 32; idx += 256) {
            int r = idx >> 5, kk = idx & 31;
            int k = k0 + kk;
            ldsA[r][kk] = (k < 200) ? xn[(size_t)(rt + r) * 200 + k] : 0.f;
        }
        for (int idx = t; idx < 32 * 128; idx += 256) {
            int kk = idx >> 7, c = idx & 127;
            int k = k0 + kk;
            ldsW[kk][c] = (k < 200) ? Wp[(size_t)k * 128 + c] : 0.f;
        }
        __syncthreads();
#pragma unroll 8
        for (int kk = 0; kk < 32; ++kk) {
            float wv = ldsW[kk][col];
#pragma unroll
            for (int r = 0; r < 16; ++r) acc[r] += ldsA[rg * 16 + r][kk] * wv;
        }
        __syncthreads();
    }
    if (gat) {
#pragma unroll
        for (int r = 0; r < 16; ++r) {
            ldsWh[rg * 16 + r][col] = acc[r];
            WhB[(size_t)(rt + rg * 16 + r) * 512 + z * 128 + col] = acc[r];
        }
        __syncthreads();
        int row = t >> 3, p = t & 7;
        const float* a = gata + z * 256;
        float s1 = 0.f, s2 = 0.f;
#pragma unroll
        for (int j = 0; j < 16; ++j) {
            int c = p * 16 + j;
            float v = ldsWh[row][c];
            s1 += v * a[c]; s2 += v * a[128 + c];
        }
        s1 += __shfl_xor(s1, 1); s1 += __shfl_xor(s1, 2); s1 += __shfl_xor(s1, 4);
        s2 += __shfl_xor(s2, 1); s2 += __shfl_xor(s2, 2); s2 += __shfl_xor(s2, 4);
        if (p == 0) { f1[z * N + rt + row] = s1; f2[z * N + rt + row] = s2; }
    } else {
        const float sc = BNF * BNF;
#pragma unroll
        for (int r = 0; r < 16; ++r)
            hbuf[(size_t)(rt + rg * 16 + r) * 128 + col] = sc * acc[r];
    }
}

// ---------------------------------------------------------------------------
// Merged: vb<1024 -> spmm1 (W=128); else -> att_head (2 per block).
// ---------------------------------------------------------------------------
__global__ void k_s1ah(const float* __restrict__ hbuf, const int* __restrict__ deg,
                       const int* __restrict__ idxs, const float* __restrict__ g1ab,
                       float* __restrict__ zbuf, const float* __restrict__ WhB,
                       const float* __restrict__ f1, const float* __restrict__ f2,
                       float* __restrict__ hcat) {
    __shared__ float eW[256];
    const int vb = blockIdx.x;
    const int t = threadIdx.x;
    if (vb < 1024) {
        const int n = vb * 2 + (t >> 7), k = t & 127;
        const int d = deg[n];
        const int* row = idxs + (size_t)n * MAXDEG;
        float a = 0.f;
        for (int j = 0; j < d; ++j) a += hbuf[(size_t)row[j] * 128 + k];
        float v = a + g1ab[k];
        v = v >= 0.f ? v : 0.01f * v;
        zbuf[(size_t)n * 128 + k] = v;
    } else {
        const int va = vb - 1024;
        const int half = t >> 7, k = t & 127;
        const int u = va * 2 + half;
        const int h = u >> 11, n = u & 2047;
        const int d = deg[n];
        const int* row = idxs + (size_t)n * MAXDEG;
        const float f1v = f1[h * N + n];
        const float* f2h = f2 + h * N;
        float* e = eW + half * 128;
        if (k < d) {
            float ev = f1v + f2h[row[k]];
            e[k] = ev >= 0.f ? ev : 0.2f * ev;
        }
        __syncthreads();
        float mx = -1e30f;
        for (int j = 0; j < d; ++j) mx = fmaxf(mx, e[j]);
        __syncthreads();
        if (k < d) e[k] = __expf(e[k] - mx);
        __syncthreads();
        float ssum = 0.f, acc = 0.f;
        for (int j = 0; j < d; ++j) ssum += e[j];
        for (int j = 0; j < d; ++j)
            acc += e[j] * WhB[(size_t)row[j] * 512 + h * 128 + k];
        float v = acc / ssum;
        v = v > 0.f ? v : __expf(v) - 1.f;
        hcat[(size_t)n * 512 + h * 128 + k] = v;
    }
}

// ---------------------------------------------------------------------------
// Merged: vb<256 -> mm g1b (zbuf@g1bW -> hbuf200); else -> mmO (+f1o/f2o).
// ---------------------------------------------------------------------------
__global__ __launch_bounds__(256) void k_g1bO(const float* __restrict__ zbuf,
                                              const float* __restrict__ g1bW,
                                              float* __restrict__ hbuf,
                                              const float* __restrict__ hcat,
                                              const float* __restrict__ outW,
                                              const float* __restrict__ outa,
                                              float* __restrict__ WhO,
                                              float* __restrict__ f1o,
                                              float* __restrict__ f2o) {
    __shared__ float ldsA[32][33];
    __shared__ float ldsW[32][65];
    const int vb = blockIdx.x;
    const int t = threadIdx.x;
    const int lane = t & 63, wg = t >> 6;
    float acc[8];
#pragma unroll
    for (int r = 0; r < 8; ++r) acc[r] = 0.f;

    if (vb < 256) {
        const int rt = (vb & 63) * 32, ct = (vb >> 6) * 64;
        for (int k0 = 0; k0 < 128; k0 += 32) {
            for (int idx = t; idx < 1024; idx += 256) {
                int r = idx >> 5, kk = idx & 31;
                ldsA[r][kk] = zbuf[(size_t)(rt + r) * 128 + k0 + kk];
            }
            for (int idx = t; idx < 2048; idx += 256) {
                int kk = idx >> 6, c = idx & 63;
                int cg = ct + c;
                ldsW[kk][c] = (cg < 200) ? g1bW[(size_t)(k0 + kk) * 200 + cg] : 0.f;
            }
            __syncthreads();
#pragma unroll 8
            for (int kk = 0; kk < 32; ++kk) {
                float wv = ldsW[kk][lane];
#pragma unroll
                for (int r = 0; r < 8; ++r) acc[r] += ldsA[wg * 8 + r][kk] * wv;
            }
            __syncthreads();
        }
        int cg = ct + lane;
        if (cg < 200) {
#pragma unroll
            for (int r = 0; r < 8; ++r)
                hbuf[(size_t)(rt + wg * 8 + r) * 200 + cg] = BNF * acc[r];
        }
    } else {
        const int rt = (vb - 256) * 32;
        for (int k0 = 0; k0 < 512; k0 += 32) {
            for (int idx = t; idx < 1024; idx += 256) {
                int r = idx >> 5, kk = idx & 31;
                ldsA[r][kk] = hcat[(size_t)(rt + r) * 512 + k0 + kk];
            }
            for (int idx = t; idx < 2048; idx += 256) {
                int kk = idx >> 6, c = idx & 63;
                ldsW[kk][c] = outW[(size_t)(k0 + kk) * 64 + c];
            }
            __syncthreads();
#pragma unroll 8
            for (int kk = 0; kk < 32; ++kk) {
                float wv = ldsW[kk][lane];
#pragma unroll
                for (int r = 0; r < 8; ++r) acc[r] += ldsA[wg * 8 + r][kk] * wv;
            }
            __syncthreads();
        }
#pragma unroll
        for (int r = 0; r < 8; ++r)
            WhO[(size_t)(rt + wg * 8 + r) * 64 + lane] = acc[r];
#pragma unroll
        for (int r = 0; r < 8; ++r) {
            float v1 = acc[r] * outa[lane];
            float v2 = acc[r] * outa[64 + lane];
#pragma unroll
            for (int off = 32; off; off >>= 1) {
                v1 += __shfl_down(v1, off);
                v2 += __shfl_down(v2, off);
            }
            if (lane == 0) { f1o[rt + wg * 8 + r] = v1; f2o[rt + wg * 8 + r] = v2; }
        }
    }
}

// ---------------------------------------------------------------------------
// Fused spmm2 + mm g2a: 16 rows/block (grid 128). xg2 kept in LDS.
// ---------------------------------------------------------------------------
__global__ __launch_bounds__(256) void k_s2g2a(const float* __restrict__ hbuf,
                                               const int* __restrict__ deg,
                                               const int* __restrict__ idxs,
                                               const float* __restrict__ g1bb,
                                               const float* __restrict__ xn,
                                               const float* __restrict__ g2aW,
                                               float* __restrict__ outp) {
    __shared__ float X[16][204];
    __shared__ float ldsW[32][128];
    const int rt = blockIdx.x * 16;
    const int t = threadIdx.x;
    {
        const int row = t >> 4, tc = t & 15;
        const int n = rt + row;
        const int d = deg[n];
        const int* rp = idxs + (size_t)n * MAXDEG;
        float a[13];
#pragma unroll
        for (int c = 0; c < 13; ++c) a[c] = 0.f;
        for (int j = 0; j < d; ++j) {
            const float* hr = hbuf + (size_t)rp[j] * 200;
#pragma unroll
            for (int c = 0; c < 13; ++c) {
                int col = tc + 16 * c;
                if (col < 200) a[c] += hr[col];
            }
        }
#pragma unroll
        for (int c = 0; c < 13; ++c) {
            int col = tc + 16 * c;
            if (col < 200) {
                float v = BNF * (a[c] + g1bb[col]);
                v = v >= 0.f ? v : 0.01f * v;
                v += BNF * xn[(size_t)n * 200 + col];
                X[row][col] = v;
            }
        }
    }
    __syncthreads();
    const int col = t & 127, rg = t >> 7;
    float acc[8];
#pragma unroll
    for (int r = 0; r < 8; ++r) acc[r] = 0.f;
    for (int k0 = 0; k0 < 200; k0 += 32) {
        for (int idx = t; idx < 4096; idx += 256) {
            int kk = idx >> 7, c = idx & 127;
            int k = k0 + kk;
            ldsW[kk][c] = (k < 200) ? g2aW[(size_t)k * 128 + c] : 0.f;
        }
        __syncthreads();
#pragma unroll 8
        for (int kk = 0; kk < 32; ++kk) {
            if (k0 + kk < 200) {
                float wv = ldsW[kk][col];
#pragma unroll
                for (int r = 0; r < 8; ++r) acc[r] += X[rg * 8 + r][k0 + kk] * wv;
            }
        }
        __syncthreads();
    }
#pragma unroll
    for (int r = 0; r < 8; ++r)
        outp[(size_t)(rt + rg * 8 + r) * 128 + col] = BNF * acc[r];
}

// ---------------------------------------------------------------------------
// Fused spmm3 + mm g2b: 16 rows/block (grid 128). z kept in LDS.
// ---------------------------------------------------------------------------
__global__ __launch_bounds__(256) void k_s3g2b(const float* __restrict__ inp,
                                               const int* __restrict__ deg,
                                               const int* __restrict__ idxs,
                                               const float* __restrict__ g2ab,
                                               const float* __restrict__ g2bW,
                                               float* __restrict__ outp) {
    __shared__ float Z[16][132];
    __shared__ float ldsW[32][65];
    const int rt = blockIdx.x * 16;
    const int t = threadIdx.x;
    {
        const int row = t >> 4, tc = t & 15;
        const int n = rt + row;
        const int d = deg[n];
        const int* rp = idxs + (size_t)n * MAXDEG;
        float a[8];
#pragma unroll
        for (int c = 0; c < 8; ++c) a[c] = 0.f;
        for (int j = 0; j < d; ++j) {
            const float* hr = inp + (size_t)rp[j] * 128;
#pragma unroll
            for (int c = 0; c < 8; ++c) a[c] += hr[tc + 16 * c];
        }
#pragma unroll
        for (int c = 0; c < 8; ++c) {
            int col = tc + 16 * c;
            float v = a[c] + g2ab[col];
            Z[row][col] = v >= 0.f ? v : 0.01f * v;
        }
    }
    __syncthreads();
    const int lane = t & 63, wg = t >> 6;
    float acc[4];
#pragma unroll
    for (int r = 0; r < 4; ++r) acc[r] = 0.f;
    for (int k0 = 0; k0 < 128; k0 += 32) {
        for (int idx = t; idx < 2048; idx += 256) {
            int kk = idx >> 6, c = idx & 63;
            ldsW[kk][c] = g2bW[(size_t)(k0 + kk) * 64 + c];
        }
        __syncthreads();
#pragma unroll 8
        for (int kk = 0; kk < 32; ++kk) {
            float wv = ldsW[kk][lane];
#pragma unroll
            for (int r = 0; r < 4; ++r) acc[r] += Z[wg * 4 + r][k0 + kk] * wv;
        }
        __syncthreads();
    }
#pragma unroll
    for (int r = 0; r < 4; ++r)
        outp[(size_t)(rt + wg * 4 + r) * 64 + lane] = BNF * acc[r];
}

// ---------------------------------------------------------------------------
// Fused spmm4 + att_out + fusion: 4 nodes/block (grid 512). GCNx in register.
// ---------------------------------------------------------------------------
__global__ void k_s4ao(const float* __restrict__ h64, const int* __restrict__ deg,
                       const int* __restrict__ idxs, const float* __restrict__ g2bb,
                       const float* __restrict__ WhO, const float* __restrict__ f1o,
                       const float* __restrict__ f2o,
                       const float* __restrict__ Wf, const float* __restrict__ bfp,
                       const float* __restrict__ cw, const float* __restrict__ cb,
                       u16* __restrict__ yT) {
    __shared__ float eW[4][MAXDEG];
    const int sub = threadIdx.x >> 6, k = threadIdx.x & 63;
    const int n = blockIdx.x * 4 + sub;
    const int d = deg[n];
    const int* row = idxs + (size_t)n * MAXDEG;
    float a = 0.f;
    for (int j = 0; j < d; ++j) a += h64[(size_t)row[j] * 64 + k];
    float g = a + g2bb[k];
    g = g >= 0.f ? g : 0.01f * g;
    g *= BNF;
    const float f1v = f1o[n];
    float* e = eW[sub];
    for (int j = k; j < d; j += 64) {
        float ev = f1v + f2o[row[j]];
        e[j] = ev >= 0.f ? ev : 0.2f * ev;
    }
    __syncthreads();
    float mx = -1e30f;
    for (int j = 0; j < d; ++j) mx = fmaxf(mx, e[j]);
    __syncthreads();
    for (int j = k; j < d; j += 64) e[j] = __expf(e[j] - mx);
    __syncthreads();
    float ssum = 0.f, acc = 0.f;
    for (int j = 0; j < d; ++j) ssum += e[j];
    for (int j = 0; j < d; ++j) acc += e[j] * WhO[(size_t)row[j] * 64 + k];
    float v = acc / ssum;
    v = v > 0.f ? v : __expf(v) - 1.f;   // elu
    v *= BNF;
    float gat = v >= 0.f ? v : 0.01f * v;
    float mn = fminf(g, gat), mxv = fmaxf(g, gat);
    float avg = g * Wf[k] + bfp[k] + gat * Wf[64 + k] + bfp[64 + k];
    float base = g + gat;
    float yv = cw[0] * (mn + base) + cw[1] * (mxv + base) + cw[2] * (avg + base) + cb[0];
    yv *= BNF;
    yv = yv >= 0.f ? yv : 0.2f * yv;
    yT[k * 2048 + n] = f2bf(yv);
}

// ---------------------------------------------------------------------------
// out[i,f] = sum_n Qbf[i,n]*yT[f,n] (round-10 proven, unchanged).
// ---------------------------------------------------------------------------
__global__ __launch_bounds__(256, 2) void k_final(const u16* __restrict__ Qbf,
                                                  const u16* __restrict__ yT,
                                                  float* __restrict__ out) {
    __shared__ __align__(16) u16 Aq[3][128 * 64];
    __shared__ __align__(16) u16 By[3][64 * 64];
    const int i0 = blockIdx.x * 128;
    const int t = threadIdx.x, w = t >> 6, l = t & 63;
    const int lrow = l >> 3;
    const int scol = (((l & 7) ^ ((l >> 3) & 7)) << 3);
    f32x4 acc[2][4];
#pragma unroll
    for (int a = 0; a < 2; ++a)
#pragma unroll
        for (int b = 0; b < 4; ++b) acc[a][b] = (f32x4){0.f, 0.f, 0.f, 0.f};

#define STAGE_F(buf, step)                                                          \
    {                                                                               \
        const size_t kc = (size_t)(step) * 64 + scol;                               \
        for (int s = w; s < 16; s += 4)                                             \
            gload16(&Qbf[(size_t)(i0 + s * 8 + lrow) * 2048 + kc],                  \
                    &Aq[buf][s * 512]);                                             \
        for (int s = w; s < 8; s += 4)                                              \
            gload16(&yT[(size_t)(s * 8 + lrow) * 2048 + kc],                        \
                    &By[buf][s * 512]);                                             \
    }

    STAGE_F(0, 0);
    STAGE_F(1, 1);
    for (int step = 0; step < 32; ++step) {
        const int cur = step % 3;
        if (step + 2 < 32) STAGE_F((step + 2) % 3, step + 2);
        if (step + 2 < 32)      asm volatile("s_waitcnt vmcnt(12)" ::: "memory");
        else if (step + 1 < 32) asm volatile("s_waitcnt vmcnt(6)"  ::: "memory");
        else                    asm volatile("s_waitcnt vmcnt(0)"  ::: "memory");
        __builtin_amdgcn_s_barrier();

        const u16* Ab = Aq[cur];
        const u16* Bb = By[cur];
#pragma unroll
        for (int sub = 0; sub < 2; ++sub) {
            const int c8 = sub * 4 + (l >> 4);
            Frag a[2];
#pragma unroll
            for (int it = 0; it < 2; ++it) {
                const int r = w * 32 + it * 16 + (l & 15);
                a[it].v = *(const short8*)&Ab[r * 64 + ((c8 ^ (r & 7)) << 3)];
            }
#pragma unroll
            for (int ft = 0; ft < 4; ++ft) {
                const int rb = ft * 16 + (l & 15);
                Frag b;
                b.v = *(const short8*)&Bb[rb * 64 + ((c8 ^ (rb & 7)) << 3)];
#pragma unroll
                for (int it = 0; it < 2; ++it)
                    acc[it][ft] = __builtin_amdgcn_mfma_f32_16x16x32_bf16(
                        a[it].v, b.v, acc[it][ft], 0, 0, 0);
            }
        }
        asm volatile("s_waitcnt lgkmcnt(0)" ::: "memory");
        __builtin_amdgcn_s_barrier();
    }
#undef STAGE_F
#pragma unroll
    for (int it = 0; it < 2; ++it)
#pragma unroll
        for (int ft = 0; ft < 4; ++ft) {
            const int i = i0 + w * 32 + it * 16 + ((l >> 4) << 2);
            const int f = ft * 16 + (l & 15);
#pragma unroll
            for (int r = 0; r < 4; ++r)
                out[(size_t)(i + r) * 64 + f] = acc[it][ft][r];
        }
}

extern "C" void kernel_launch(void* const* d_in, const int* in_sizes, int n_in,
                              void* d_out, int out_size, void* d_ws, size_t ws_size,
                              hipStream_t stream) {
    const float* x     = (const float*)d_in[0];
    const float* adj   = (const float*)d_in[1];
    const float* Q     = (const float*)d_in[2];
    const float* g1aW  = (const float*)d_in[3];
    const float* g1ab  = (const float*)d_in[4];
    const float* g1bW  = (const float*)d_in[5];
    const float* g1bb  = (const float*)d_in[6];
    const float* g2aW  = (const float*)d_in[7];
    const float* g2ab  = (const float*)d_in[8];
    const float* g2bW  = (const float*)d_in[9];
    const float* g2bb  = (const float*)d_in[10];
    const float* gatW  = (const float*)d_in[11];
    const float* gata  = (const float*)d_in[12];
    const float* outW  = (const float*)d_in[13];
    const float* outa  = (const float*)d_in[14];
    const float* Wf    = (const float*)d_in[15];
    const float* bfp   = (const float*)d_in[16];
    const float* convw = (const float*)d_in[17];
    const float* convb = (const float*)d_in[18];

    float* ws   = (float*)d_ws;
    float* xn   = ws + 411648;
    float* hbuf = ws + 1640448;
    float* zbuf = ws + 2050048;
    float* WhO  = ws + 2312192;
    float* f1   = ws + 2836480;
    float* f2   = ws + 2844672;
    float* f1o  = ws + 2852864;
    float* f2o  = ws + 2854912;
    int*   deg  = (int*)(ws + 2856960);
    int*   idxs = (int*)(ws + 2859008);   // ends 3055616
    u16*   yT   = (u16*)(ws + 3300000);
    float* csPart = ws + 3600000;
    float* S_part = ws + 4200000;         // 52 MB
    u16*   Qbf    = (u16*)(ws + 71308864);
    u16*   xfT    = (u16*)(ws + 138417728);

    float* out  = (float*)d_out;
    float* WhB  = out;             // 2048*512 scratch inside d_out
    float* hcat = out + 1048576;   // 2048*512 scratch inside d_out

    // ---- conversion (+CSR co-scheduled) + big S GEMM ----
    k_convX<<<1024, 256, 0, stream>>>(x, xfT, adj, deg, idxs);
    k_bigS<<<1024, 256, 0, stream>>>(Q, xfT, Qbf, S_part, csPart);
    k_redS<<<1600, 256, 0, stream>>>(S_part, csPart, xn);

    // ---- GNN mid-section: 6 launches ----
    k_wh5<<<dim3(64, 5), 256, 0, stream>>>(xn, gatW, gata, g1aW, WhB, f1, f2, hbuf);
    k_s1ah<<<5120, 256, 0, stream>>>(hbuf, deg, idxs, g1ab, zbuf, WhB, f1, f2, hcat);
    k_g1bO<<<320, 256, 0, stream>>>(zbuf, g1bW, hbuf, hcat, outW, outa, WhO, f1o, f2o);
    k_s2g2a<<<128, 256, 0, stream>>>(hbuf, deg, idxs, g1bb, xn, g2aW, zbuf);
    k_s3g2b<<<128, 256, 0, stream>>>(zbuf, deg, idxs, g2ab, g2bW, hbuf);
    k_s4ao<<<512, 256, 0, stream>>>(hbuf, deg, idxs, g2bb, WhO, f1o, f2o,
                                    Wf, bfp, convw, convb, yT);

    // ---- final projection (overwrites WhB/hcat scratch in d_out) ----
    k_final<<<512, 256, 0, stream>>>(Qbf, yT, out);
}

// Round 16
// 635.477 us; speedup vs baseline: 1.4463x; 1.0548x over previous
//
#include <hip/hip_runtime.h>
#include <math.h>

#define BNF 0.9999950000374997f

constexpr int N    = 2048;
constexpr int C    = 200;
constexpr int HW   = 65536;
constexpr int MAXDEG = 96;

typedef unsigned short u16;
typedef __attribute__((ext_vector_type(8))) short short8;
typedef __attribute__((ext_vector_type(4))) float f32x4;

union Frag  { short8 v; ushort4 h[2]; };
union FragA { short8 v; uint2 u2[2]; };

__device__ inline u16 f2bf(float x) {
    unsigned int u = __float_as_uint(x);
    unsigned int r = (u + 0x7fffu + ((u >> 16) & 1u)) >> 16;
    return (u16)r;
}

__device__ __forceinline__ void gload16(const void* g, void* l) {
    __builtin_amdgcn_global_load_lds(
        (const __attribute__((address_space(1))) unsigned int*)g,
        (__attribute__((address_space(3))) unsigned int*)l, 16, 0, 0);
}

// ---------------------------------------------------------------------------
// blocks 0..511: xf -> xfT [208][65536] bf16 (rows 200..207 zeroed)
// blocks 512..1023: CSR build
// ---------------------------------------------------------------------------
__global__ __launch_bounds__(256) void k_convX(const float* __restrict__ xf,
                                               u16* __restrict__ xfT,
                                               const float* __restrict__ adj,
                                               int* __restrict__ deg,
                                               int* __restrict__ idxs) {
    const int t = threadIdx.x;
    if (blockIdx.x >= 512) {
        int w = t >> 6, lane = t & 63;
        int n = (blockIdx.x - 512) * 4 + w;
        const float* row = adj + (size_t)n * N;
        int base = 0;
        for (int c = 0; c < N; c += 64) {
            float v = row[c + lane];
            bool p = v > 0.f;
            unsigned long long m = __ballot(p);
            int pos = __popcll(m & ((1ull << lane) - 1ull));
            if (p && (base + pos) < MAXDEG)
                idxs[(size_t)n * MAXDEG + base + pos] = c + lane;
            base += __popcll(m);
        }
        if (lane == 0) deg[n] = base < MAXDEG ? base : MAXDEG;
        return;
    }
    __shared__ __align__(16) u16 T2[200][140];
    const int i0 = blockIdx.x * 128;
    for (int p = 0; p < 25; ++p) {
        int idx = p * 256 + t;
        int il = idx / 50, cq = idx % 50;
        float4 v = *(const float4*)&xf[(size_t)(i0 + il) * 200 + cq * 4];
        T2[cq * 4 + 0][il] = f2bf(v.x);
        T2[cq * 4 + 1][il] = f2bf(v.y);
        T2[cq * 4 + 2][il] = f2bf(v.z);
        T2[cq * 4 + 3][il] = f2bf(v.w);
    }
    __syncthreads();
    for (int p = 0; p < 13; ++p) {
        int c = p * 16 + (t >> 4);
        if (c < 200) {
            int io = (t & 15) * 8;
            u16* dst = &xfT[(size_t)c * 65536 + i0 + io];
            *(ushort4*)&dst[0] = *(const ushort4*)&T2[c][io];
            *(ushort4*)&dst[4] = *(const ushort4*)&T2[c][io + 4];
        }
    }
    ushort4 z4 = {0, 0, 0, 0};
    for (int idx = t; idx < 8 * 16; idx += 256) {
        int r = 200 + (idx >> 4), io = (idx & 15) * 8;
        u16* dst = &xfT[(size_t)r * 65536 + i0 + io];
        *(ushort4*)&dst[0] = z4;
        *(ushort4*)&dst[4] = z4;
    }
}

// ---------------------------------------------------------------------------
// Fused conversion + S-partial GEMM (round-10/13 proven schedule).
// ks-splits 32 -> 16 (grid 512, 128 K-steps/block): halves S_part traffic.
// ---------------------------------------------------------------------------
__global__ __launch_bounds__(256, 3) void k_bigS(const float* __restrict__ Q,
                                                 const u16* __restrict__ xfT,
                                                 u16* __restrict__ Qbf,
                                                 float* __restrict__ S_part,
                                                 float* __restrict__ csPart) {
    __shared__ __align__(16) u16 Bt[2][208 * 32];
    __shared__ __align__(16) u16 At[64 * 34];
    const int bid = blockIdx.x;
    const int xcd = bid & 7, jb = bid >> 3;          // jb 0..63
    const int nt_b = jb & 31;
    const int ks_b = ((jb >> 5) << 3) + xcd;         // 16 slabs, same-slab -> same XCD
    const int n0 = nt_b * 64;
    const size_t i0 = (size_t)ks_b * 4096;
    const int t = threadIdx.x, w = t >> 6, l = t & 63;
    const int ct0 = (w == 0) ? 0 : (4 + (w - 1) * 3);
    const int nct = (w == 0) ? 4 : 3;
    const int lrowB = l >> 2;
    const int scolB = (((l & 3) ^ ((l >> 3) & 3)) << 3);
    const int nq = t & 15;
    const int kp = t >> 4;

    f32x4 acc[4][4];
#pragma unroll
    for (int a = 0; a < 4; ++a)
#pragma unroll
        for (int b = 0; b < 4; ++b) acc[a][b] = (f32x4){0.f, 0.f, 0.f, 0.f};
    float csum[4] = {0.f, 0.f, 0.f, 0.f};

    float4 aq0, ar0, aq1, ar1;

#define ISSUE_B(PAR, STEP)                                                      \
    {                                                                           \
        const size_t kc = i0 + (size_t)(STEP) * 32 + scolB;                     \
        for (int s = w; s < 13; s += 4)                                         \
            gload16(&xfT[(size_t)(s * 16 + lrowB) * 65536 + kc],                \
                    &Bt[PAR][s * 512]);                                         \
    }

#define LOAD_A(AQ, AR, STEP)                                                    \
    {                                                                           \
        const float* qp = &Q[(i0 + (size_t)(STEP) * 32 + kp * 2) * 2048         \
                             + n0 + nq * 4];                                    \
        AQ = *(const float4*)qp;                                                \
        AR = *(const float4*)(qp + 2048);                                       \
    }

#define WRITE_A(AQ, AR, STEP)                                                   \
    {                                                                           \
        const float* ca = (const float*)&AQ;                                    \
        const float* cb = (const float*)&AR;                                    \
        ushort4 s0, s1;                                                         \
        u16* q0 = (u16*)&s0; u16* q1 = (u16*)&s1;                               \
        _Pragma("unroll")                                                       \
        for (int jj = 0; jj < 4; ++jj) {                                        \
            const int n_ = nq * 4 + jj;                                         \
            ushort2 p2;                                                         \
            p2.x = f2bf(ca[jj]); p2.y = f2bf(cb[jj]);                           \
            *(ushort2*)&At[n_ * 34 + ((n_ & 1) << 1) + kp * 2] = p2;            \
            csum[jj] += ca[jj] + cb[jj];                                        \
            q0[jj] = p2.x; q1[jj] = p2.y;                                       \
        }                                                                       \
        const size_t r0 = i0 + (size_t)(STEP) * 32 + kp * 2;                    \
        *(ushort4*)&Qbf[r0 * 2048 + n0 + nq * 4] = s0;                          \
        *(ushort4*)&Qbf[(r0 + 1) * 2048 + n0 + nq * 4] = s1;                    \
    }

#define MFMA_PHASE(PAR)                                                         \
    {                                                                           \
        const u16* Bb = Bt[PAR];                                                \
        const int g = l >> 4;                                                   \
        FragA af[4];                                                            \
        _Pragma("unroll")                                                       \
        for (int nt = 0; nt < 4; ++nt) {                                        \
            const int r = nt * 16 + (l & 15);                                   \
            const int ab = r * 34 + ((r & 1) << 1) + g * 8;                     \
            af[nt].u2[0] = *(const uint2*)&At[ab];                              \
            af[nt].u2[1] = *(const uint2*)&At[ab + 4];                          \
        }                                                                       \
        _Pragma("unroll")                                                       \
        for (int c = 0; c < 4; ++c) {                                           \
            if (c < nct) {                                                      \
                const int rb = (ct0 + c) * 16 + (l & 15);                       \
                Frag bf;                                                        \
                bf.v = *(const short8*)&Bb[rb * 32 + ((g ^ ((rb >> 1) & 3)) << 3)]; \
                _Pragma("unroll")                                               \
                for (int nt = 0; nt < 4; ++nt)                                  \
                    acc[nt][c] = __builtin_amdgcn_mfma_f32_16x16x32_bf16(       \
                        af[nt].v, bf.v, acc[nt][c], 0, 0, 0);                   \
            }                                                                   \
        }                                                                       \
    }

#define STEPBODY(STEP, PAR, NPAR, CQ, CR, COND)                                 \
    {                                                                           \
        if (COND) ISSUE_B(NPAR, (STEP) + 1);                                    \
        WRITE_A(CQ, CR, STEP);                                                  \
        {                                                                       \
            const int nst = ((STEP) + 2 > 127) ? 127 : (STEP) + 2;              \
            LOAD_A(CQ, CR, nst);                                                \
        }                                                                       \
        asm volatile("s_waitcnt lgkmcnt(0)" ::: "memory");                      \
        __builtin_amdgcn_s_barrier();                                           \
        if (COND) {                                                             \
            if (w == 0) asm volatile("s_waitcnt vmcnt(12)" ::: "memory");       \
            else        asm volatile("s_waitcnt vmcnt(11)" ::: "memory");       \
        } else {                                                                \
            asm volatile("s_waitcnt vmcnt(0)" ::: "memory");                    \
        }                                                                       \
        MFMA_PHASE(PAR);                                                        \
        __builtin_amdgcn_s_barrier();                                           \
    }

    ISSUE_B(0, 0);
    LOAD_A(aq0, ar0, 0);
    LOAD_A(aq1, ar1, 1);

    for (int s2 = 0; s2 < 64; ++s2) {
        STEPBODY(s2 * 2,     0, 1, aq0, ar0, true);
        STEPBODY(s2 * 2 + 1, 1, 0, aq1, ar1, (s2 < 63));
    }
#undef STEPBODY
#undef MFMA_PHASE
#undef WRITE_A
#undef LOAD_A
#undef ISSUE_B

    __syncthreads();
    float* csF = (float*)At;
#pragma unroll
    for (int jj = 0; jj < 4; ++jj)
        csF[kp * 64 + nq * 4 + jj] = csum[jj];
    __syncthreads();
    if (t < 64) {
        float s = 0.f;
#pragma unroll
        for (int g2 = 0; g2 < 16; ++g2) s += csF[g2 * 64 + t];
        csPart[(size_t)ks_b * 2048 + n0 + t] = s;
    }
    float* Sp = S_part + (size_t)ks_b * 409600;
#pragma unroll
    for (int nt = 0; nt < 4; ++nt)
#pragma unroll
        for (int c = 0; c < 4; ++c) {
            if (c < nct) {
                const int cc = (ct0 + c) * 16 + (l & 15);
                if (cc < 200) {
                    const int nbase = n0 + nt * 16 + ((l >> 4) << 2);
#pragma unroll
                    for (int r = 0; r < 4; ++r)
                        Sp[(size_t)(nbase + r) * 200 + cc] = acc[nt][c][r];
                }
            }
        }
}

// xn = BN * (sum S_part) / (sum csPart)   (16 slabs)
__global__ void k_redS(const float* __restrict__ S_part, const float* __restrict__ csPart,
                       float* __restrict__ xn) {
    int i = blockIdx.x * 256 + threadIdx.x;
    if (i >= N * C) return;
    int n = i / C;
    float s = 0.f, csn = 0.f;
#pragma unroll 8
    for (int p = 0; p < 16; ++p) s += S_part[(size_t)p * 409600 + i];
#pragma unroll 8
    for (int p = 0; p < 16; ++p) csn += csPart[(size_t)p * 2048 + n];
    xn[i] = BNF * s / csn;
}

// ---------------------------------------------------------------------------
// Merged: z<4 -> GAT Wh head z (+f1/f2 epilogue); z==4 -> GCN mm1 (BNF^2).
// ---------------------------------------------------------------------------
__global__ __launch_bounds__(256) void k_wh5(const float* __restrict__ xn,
                                             const float* __restrict__ gatW,
                                             const float* __restrict__ gata,
                                             const float* __restrict__ g1aW,
                                             float* __restrict__ WhB,
                                             float* __restrict__ f1,
                                             float* __restrict__ f2,
                                             float* __restrict__ hbuf) {
    __shared__ float ldsA[32][33];
    __shared__ float ldsW[32][128];
    __shared__ float ldsWh[32][129];
    const int rt = blockIdx.x * 32;
    const int z  = blockIdx.y;
    const bool gat = z < 4;
    const float* Wp = gat ? gatW + (size_t)z * 25600 : g1aW;
    const int t = threadIdx.x;
    const int col = t & 127, rg = t >> 7;
    float acc[16];
#pragma unroll
    for (int r = 0; r < 16; ++r) acc[r] = 0.f;

    for (int k0 = 0; k0 < 200; k0 += 32) {
        for (int idx = t; idx < 32 * 32; idx += 256) {
            int r = idx >> 5, kk = idx & 31;
            int k = k0 + kk;
            ldsA[r][kk] = (k < 200) ? xn[(size_t)(rt + r) * 200 + k] : 0.f;
        }
        for (int idx = t; idx < 32 * 128; idx += 256) {
            int kk = idx >> 7, c = idx & 127;
            int k = k0 + kk;
            ldsW[kk][c] = (k < 200) ? Wp[(size_t)k * 128 + c] : 0.f;
        }
        __syncthreads();
#pragma unroll 8
        for (int kk = 0; kk < 32; ++kk) {
            float wv = ldsW[kk][col];
#pragma unroll
            for (int r = 0; r < 16; ++r) acc[r] += ldsA[rg * 16 + r][kk] * wv;
        }
        __syncthreads();
    }
    if (gat) {
#pragma unroll
        for (int r = 0; r < 16; ++r) {
            ldsWh[rg * 16 + r][col] = acc[r];
            WhB[(size_t)(rt + rg * 16 + r) * 512 + z * 128 + col] = acc[r];
        }
        __syncthreads();
        int row = t >> 3, p = t & 7;
        const float* a = gata + z * 256;
        float s1 = 0.f, s2 = 0.f;
#pragma unroll
        for (int j = 0; j < 16; ++j) {
            int c = p * 16 + j;
            float v = ldsWh[row][c];
            s1 += v * a[c]; s2 += v * a[128 + c];
        }
        s1 += __shfl_xor(s1, 1); s1 += __shfl_xor(s1, 2); s1 += __shfl_xor(s1, 4);
        s2 += __shfl_xor(s2, 1); s2 += __shfl_xor(s2, 2); s2 += __shfl_xor(s2, 4);
        if (p == 0) { f1[z * N + rt + row] = s1; f2[z * N + rt + row] = s2; }
    } else {
        const float sc = BNF * BNF;
#pragma unroll
        for (int r = 0; r < 16; ++r)
            hbuf[(size_t)(rt + rg * 16 + r) * 128 + col] = sc * acc[r];
    }
}

// ---------------------------------------------------------------------------
// Merged: vb<1024 -> spmm1 (W=128); else -> att_head (2 per block).
// ---------------------------------------------------------------------------
__global__ void k_s1ah(const float* __restrict__ hbuf, const int* __restrict__ deg,
                       const int* __restrict__ idxs, const float* __restrict__ g1ab,
                       float* __restrict__ zbuf, const float* __restrict__ WhB,
                       const float* __restrict__ f1, const float* __restrict__ f2,
                       float* __restrict__ hcat) {
    __shared__ float eW[256];
    const int vb = blockIdx.x;
    const int t = threadIdx.x;
    if (vb < 1024) {
        const int n = vb * 2 + (t >> 7), k = t & 127;
        const int d = deg[n];
        const int* row = idxs + (size_t)n * MAXDEG;
        float a = 0.f;
        for (int j = 0; j < d; ++j) a += hbuf[(size_t)row[j] * 128 + k];
        float v = a + g1ab[k];
        v = v >= 0.f ? v : 0.01f * v;
        zbuf[(size_t)n * 128 + k] = v;
    } else {
        const int va = vb - 1024;
        const int half = t >> 7, k = t & 127;
        const int u = va * 2 + half;
        const int h = u >> 11, n = u & 2047;
        const int d = deg[n];
        const int* row = idxs + (size_t)n * MAXDEG;
        const float f1v = f1[h * N + n];
        const float* f2h = f2 + h * N;
        float* e = eW + half * 128;
        if (k < d) {
            float ev = f1v + f2h[row[k]];
            e[k] = ev >= 0.f ? ev : 0.2f * ev;
        }
        __syncthreads();
        float mx = -1e30f;
        for (int j = 0; j < d; ++j) mx = fmaxf(mx, e[j]);
        __syncthreads();
        if (k < d) e[k] = __expf(e[k] - mx);
        __syncthreads();
        float ssum = 0.f, acc = 0.f;
        for (int j = 0; j < d; ++j) ssum += e[j];
        for (int j = 0; j < d; ++j)
            acc += e[j] * WhB[(size_t)row[j] * 512 + h * 128 + k];
        float v = acc / ssum;
        v = v > 0.f ? v : __expf(v) - 1.f;
        hcat[(size_t)n * 512 + h * 128 + k] = v;
    }
}

// ---------------------------------------------------------------------------
// Merged: vb<256 -> mm g1b (zbuf@g1bW -> hbuf200); else -> mmO (+f1o/f2o).
// ---------------------------------------------------------------------------
__global__ __launch_bounds__(256) void k_g1bO(const float* __restrict__ zbuf,
                                              const float* __restrict__ g1bW,
                                              float* __restrict__ hbuf,
                                              const float* __restrict__ hcat,
                                              const float* __restrict__ outW,
                                              const float* __restrict__ outa,
                                              float* __restrict__ WhO,
                                              float* __restrict__ f1o,
                                              float* __restrict__ f2o) {
    __shared__ float ldsA[32][33];
    __shared__ float ldsW[32][65];
    const int vb = blockIdx.x;
    const int t = threadIdx.x;
    const int lane = t & 63, wg = t >> 6;
    float acc[8];
#pragma unroll
    for (int r = 0; r < 8; ++r) acc[r] = 0.f;

    if (vb < 256) {
        const int rt = (vb & 63) * 32, ct = (vb >> 6) * 64;
        for (int k0 = 0; k0 < 128; k0 += 32) {
            for (int idx = t; idx < 1024; idx += 256) {
                int r = idx >> 5, kk = idx & 31;
                ldsA[r][kk] = zbuf[(size_t)(rt + r) * 128 + k0 + kk];
            }
            for (int idx = t; idx < 2048; idx += 256) {
                int kk = idx >> 6, c = idx & 63;
                int cg = ct + c;
                ldsW[kk][c] = (cg < 200) ? g1bW[(size_t)(k0 + kk) * 200 + cg] : 0.f;
            }
            __syncthreads();
#pragma unroll 8
            for (int kk = 0; kk < 32; ++kk) {
                float wv = ldsW[kk][lane];
#pragma unroll
                for (int r = 0; r < 8; ++r) acc[r] += ldsA[wg * 8 + r][kk] * wv;
            }
            __syncthreads();
        }
        int cg = ct + lane;
        if (cg < 200) {
#pragma unroll
            for (int r = 0; r < 8; ++r)
                hbuf[(size_t)(rt + wg * 8 + r) * 200 + cg] = BNF * acc[r];
        }
    } else {
        const int rt = (vb - 256) * 32;
        for (int k0 = 0; k0 < 512; k0 += 32) {
            for (int idx = t; idx < 1024; idx += 256) {
                int r = idx >> 5, kk = idx & 31;
                ldsA[r][kk] = hcat[(size_t)(rt + r) * 512 + k0 + kk];
            }
            for (int idx = t; idx < 2048; idx += 256) {
                int kk = idx >> 6, c = idx & 63;
                ldsW[kk][c] = outW[(size_t)(k0 + kk) * 64 + c];
            }
            __syncthreads();
#pragma unroll 8
            for (int kk = 0; kk < 32; ++kk) {
                float wv = ldsW[kk][lane];
#pragma unroll
                for (int r = 0; r < 8; ++r) acc[r] += ldsA[wg * 8 + r][kk] * wv;
            }
            __syncthreads();
        }
#pragma unroll
        for (int r = 0; r < 8; ++r)
            WhO[(size_t)(rt + wg * 8 + r) * 64 + lane] = acc[r];
#pragma unroll
        for (int r = 0; r < 8; ++r) {
            float v1 = acc[r] * outa[lane];
            float v2 = acc[r] * outa[64 + lane];
#pragma unroll
            for (int off = 32; off; off >>= 1) {
                v1 += __shfl_down(v1, off);
                v2 += __shfl_down(v2, off);
            }
            if (lane == 0) { f1o[rt + wg * 8 + r] = v1; f2o[rt + wg * 8 + r] = v2; }
        }
    }
}

// ---------------------------------------------------------------------------
// Fused spmm2 + mm g2a: 16 rows/block (grid 128). xg2 kept in LDS.
// ---------------------------------------------------------------------------
__global__ __launch_bounds__(256) void k_s2g2a(const float* __restrict__ hbuf,
                                               const int* __restrict__ deg,
                                               const int* __restrict__ idxs,
                                               const float* __restrict__ g1bb,
                                               const float* __restrict__ xn,
                                               const float* __restrict__ g2aW,
                                               float* __restrict__ outp) {
    __shared__ float X[16][204];
    __shared__ float ldsW[32][128];
    const int rt = blockIdx.x * 16;
    const int t = threadIdx.x;
    {
        const int row = t >> 4, tc = t & 15;
        const int n = rt + row;
        const int d = deg[n];
        const int* rp = idxs + (size_t)n * MAXDEG;
        float a[13];
#pragma unroll
        for (int c = 0; c < 13; ++c) a[c] = 0.f;
        for (int j = 0; j < d; ++j) {
            const float* hr = hbuf + (size_t)rp[j] * 200;
#pragma unroll
            for (int c = 0; c < 13; ++c) {
                int col = tc + 16 * c;
                if (col < 200) a[c] += hr[col];
            }
        }
#pragma unroll
        for (int c = 0; c < 13; ++c) {
            int col = tc + 16 * c;
            if (col < 200) {
                float v = BNF * (a[c] + g1bb[col]);
                v = v >= 0.f ? v : 0.01f * v;
                v += BNF * xn[(size_t)n * 200 + col];
                X[row][col] = v;
            }
        }
    }
    __syncthreads();
    const int col = t & 127, rg = t >> 7;
    float acc[8];
#pragma unroll
    for (int r = 0; r < 8; ++r) acc[r] = 0.f;
    for (int k0 = 0; k0 < 200; k0 += 32) {
        for (int idx = t; idx < 4096; idx += 256) {
            int kk = idx >> 7, c = idx & 127;
            int k = k0 + kk;
            ldsW[kk][c] = (k < 200) ? g2aW[(size_t)k * 128 + c] : 0.f;
        }
        __syncthreads();
#pragma unroll 8
        for (int kk = 0; kk < 32; ++kk) {
            if (k0 + kk < 200) {
                float wv = ldsW[kk][col];
#pragma unroll
                for (int r = 0; r < 8; ++r) acc[r] += X[rg * 8 + r][k0 + kk] * wv;
            }
        }
        __syncthreads();
    }
#pragma unroll
    for (int r = 0; r < 8; ++r)
        outp[(size_t)(rt + rg * 8 + r) * 128 + col] = BNF * acc[r];
}

// ---------------------------------------------------------------------------
// Fused spmm3 + mm g2b: 16 rows/block (grid 128). z kept in LDS.
// ---------------------------------------------------------------------------
__global__ __launch_bounds__(256) void k_s3g2b(const float* __restrict__ inp,
                                               const int* __restrict__ deg,
                                               const int* __restrict__ idxs,
                                               const float* __restrict__ g2ab,
                                               const float* __restrict__ g2bW,
                                               float* __restrict__ outp) {
    __shared__ float Z[16][132];
    __shared__ float ldsW[32][65];
    const int rt = blockIdx.x * 16;
    const int t = threadIdx.x;
    {
        const int row = t >> 4, tc = t & 15;
        const int n = rt + row;
        const int d = deg[n];
        const int* rp = idxs + (size_t)n * MAXDEG;
        float a[8];
#pragma unroll
        for (int c = 0; c < 8; ++c) a[c] = 0.f;
        for (int j = 0; j < d; ++j) {
            const float* hr = inp + (size_t)rp[j] * 128;
#pragma unroll
            for (int c = 0; c < 8; ++c) a[c] += hr[tc + 16 * c];
        }
#pragma unroll
        for (int c = 0; c < 8; ++c) {
            int col = tc + 16 * c;
            float v = a[c] + g2ab[col];
            Z[row][col] = v >= 0.f ? v : 0.01f * v;
        }
    }
    __syncthreads();
    const int lane = t & 63, wg = t >> 6;
    float acc[4];
#pragma unroll
    for (int r = 0; r < 4; ++r) acc[r] = 0.f;
    for (int k0 = 0; k0 < 128; k0 += 32) {
        for (int idx = t; idx < 2048; idx += 256) {
            int kk = idx >> 6, c = idx & 63;
            ldsW[kk][c] = g2bW[(size_t)(k0 + kk) * 64 + c];
        }
        __syncthreads();
#pragma unroll 8
        for (int kk = 0; kk < 32; ++kk) {
            float wv = ldsW[kk][lane];
#pragma unroll
            for (int r = 0; r < 4; ++r) acc[r] += Z[wg * 4 + r][k0 + kk] * wv;
        }
        __syncthreads();
    }
#pragma unroll
    for (int r = 0; r < 4; ++r)
        outp[(size_t)(rt + wg * 4 + r) * 64 + lane] = BNF * acc[r];
}

// ---------------------------------------------------------------------------
// Fused spmm4 + att_out + fusion: 4 nodes/block (grid 512). GCNx in register.
// ---------------------------------------------------------------------------
__global__ void k_s4ao(const float* __restrict__ h64, const int* __restrict__ deg,
                       const int* __restrict__ idxs, const float* __restrict__ g2bb,
                       const float* __restrict__ WhO, const float* __restrict__ f1o,
                       const float* __restrict__ f2o,
                       const float* __restrict__ Wf, const float* __restrict__ bfp,
                       const float* __restrict__ cw, const float* __restrict__ cb,
                       u16* __restrict__ yT) {
    __shared__ float eW[4][MAXDEG];
    const int sub = threadIdx.x >> 6, k = threadIdx.x & 63;
    const int n = blockIdx.x * 4 + sub;
    const int d = deg[n];
    const int* row = idxs + (size_t)n * MAXDEG;
    float a = 0.f;
    for (int j = 0; j < d; ++j) a += h64[(size_t)row[j] * 64 + k];
    float g = a + g2bb[k];
    g = g >= 0.f ? g : 0.01f * g;
    g *= BNF;
    const float f1v = f1o[n];
    float* e = eW[sub];
    for (int j = k; j < d; j += 64) {
        float ev = f1v + f2o[row[j]];
        e[j] = ev >= 0.f ? ev : 0.2f * ev;
    }
    __syncthreads();
    float mx = -1e30f;
    for (int j = 0; j < d; ++j) mx = fmaxf(mx, e[j]);
    __syncthreads();
    for (int j = k; j < d; j += 64) e[j] = __expf(e[j] - mx);
    __syncthreads();
    float ssum = 0.f, acc = 0.f;
    for (int j = 0; j < d; ++j) ssum += e[j];
    for (int j = 0; j < d; ++j) acc += e[j] * WhO[(size_t)row[j] * 64 + k];
    float v = acc / ssum;
    v = v > 0.f ? v : __expf(v) - 1.f;   // elu
    v *= BNF;
    float gat = v >= 0.f ? v : 0.01f * v;
    float mn = fminf(g, gat), mxv = fmaxf(g, gat);
    float avg = g * Wf[k] + bfp[k] + gat * Wf[64 + k] + bfp[64 + k];
    float base = g + gat;
    float yv = cw[0] * (mn + base) + cw[1] * (mxv + base) + cw[2] * (avg + base) + cb[0];
    yv *= BNF;
    yv = yv >= 0.f ? yv : 0.2f * yv;
    yT[k * 2048 + n] = f2bf(yv);
}

// ---------------------------------------------------------------------------
// out[i,f] = sum_n Qbf[i,n]*yT[f,n] (round-10 proven, unchanged).
// ---------------------------------------------------------------------------
__global__ __launch_bounds__(256, 2) void k_final(const u16* __restrict__ Qbf,
                                                  const u16* __restrict__ yT,
                                                  float* __restrict__ out) {
    __shared__ __align__(16) u16 Aq[3][128 * 64];
    __shared__ __align__(16) u16 By[3][64 * 64];
    const int i0 = blockIdx.x * 128;
    const int t = threadIdx.x, w = t >> 6, l = t & 63;
    const int lrow = l >> 3;
    const int scol = (((l & 7) ^ ((l >> 3) & 7)) << 3);
    f32x4 acc[2][4];
#pragma unroll
    for (int a = 0; a < 2; ++a)
#pragma unroll
        for (int b = 0; b < 4; ++b) acc[a][b] = (f32x4){0.f, 0.f, 0.f, 0.f};

#define STAGE_F(buf, step)                                                          \
    {                                                                               \
        const size_t kc = (size_t)(step) * 64 + scol;                               \
        for (int s = w; s < 16; s += 4)                                             \
            gload16(&Qbf[(size_t)(i0 + s * 8 + lrow) * 2048 + kc],                  \
                    &Aq[buf][s * 512]);                                             \
        for (int s = w; s < 8; s += 4)                                              \
            gload16(&yT[(size_t)(s * 8 + lrow) * 2048 + kc],                        \
                    &By[buf][s * 512]);                                             \
    }

    STAGE_F(0, 0);
    STAGE_F(1, 1);
    for (int step = 0; step < 32; ++step) {
        const int cur = step % 3;
        if (step + 2 < 32) STAGE_F((step + 2) % 3, step + 2);
        if (step + 2 < 32)      asm volatile("s_waitcnt vmcnt(12)" ::: "memory");
        else if (step + 1 < 32) asm volatile("s_waitcnt vmcnt(6)"  ::: "memory");
        else                    asm volatile("s_waitcnt vmcnt(0)"  ::: "memory");
        __builtin_amdgcn_s_barrier();

        const u16* Ab = Aq[cur];
        const u16* Bb = By[cur];
#pragma unroll
        for (int sub = 0; sub < 2; ++sub) {
            const int c8 = sub * 4 + (l >> 4);
            Frag a[2];
#pragma unroll
            for (int it = 0; it < 2; ++it) {
                const int r = w * 32 + it * 16 + (l & 15);
                a[it].v = *(const short8*)&Ab[r * 64 + ((c8 ^ (r & 7)) << 3)];
            }
#pragma unroll
            for (int ft = 0; ft < 4; ++ft) {
                const int rb = ft * 16 + (l & 15);
                Frag b;
                b.v = *(const short8*)&Bb[rb * 64 + ((c8 ^ (rb & 7)) << 3)];
#pragma unroll
                for (int it = 0; it < 2; ++it)
                    acc[it][ft] = __builtin_amdgcn_mfma_f32_16x16x32_bf16(
                        a[it].v, b.v, acc[it][ft], 0, 0, 0);
            }
        }
        asm volatile("s_waitcnt lgkmcnt(0)" ::: "memory");
        __builtin_amdgcn_s_barrier();
    }
#undef STAGE_F
#pragma unroll
    for (int it = 0; it < 2; ++it)
#pragma unroll
        for (int ft = 0; ft < 4; ++ft) {
            const int i = i0 + w * 32 + it * 16 + ((l >> 4) << 2);
            const int f = ft * 16 + (l & 15);
#pragma unroll
            for (int r = 0; r < 4; ++r)
                out[(size_t)(i + r) * 64 + f] = acc[it][ft][r];
        }
}

extern "C" void kernel_launch(void* const* d_in, const int* in_sizes, int n_in,
                              void* d_out, int out_size, void* d_ws, size_t ws_size,
                              hipStream_t stream) {
    const float* x     = (const float*)d_in[0];
    const float* adj   = (const float*)d_in[1];
    const float* Q     = (const float*)d_in[2];
    const float* g1aW  = (const float*)d_in[3];
    const float* g1ab  = (const float*)d_in[4];
    const float* g1bW  = (const float*)d_in[5];
    const float* g1bb  = (const float*)d_in[6];
    const float* g2aW  = (const float*)d_in[7];
    const float* g2ab  = (const float*)d_in[8];
    const float* g2bW  = (const float*)d_in[9];
    const float* g2bb  = (const float*)d_in[10];
    const float* gatW  = (const float*)d_in[11];
    const float* gata  = (const float*)d_in[12];
    const float* outW  = (const float*)d_in[13];
    const float* outa  = (const float*)d_in[14];
    const float* Wf    = (const float*)d_in[15];
    const float* bfp   = (const float*)d_in[16];
    const float* convw = (const float*)d_in[17];
    const float* convb = (const float*)d_in[18];

    float* ws   = (float*)d_ws;
    float* xn   = ws + 411648;
    float* hbuf = ws + 1640448;
    float* zbuf = ws + 2050048;
    float* WhO  = ws + 2312192;
    float* f1   = ws + 2836480;
    float* f2   = ws + 2844672;
    float* f1o  = ws + 2852864;
    float* f2o  = ws + 2854912;
    int*   deg  = (int*)(ws + 2856960);
    int*   idxs = (int*)(ws + 2859008);   // ends 3055616
    u16*   yT   = (u16*)(ws + 3300000);
    float* csPart = ws + 3600000;         // 16*2048 f32
    float* S_part = ws + 4200000;         // 16*409600 f32 = 26 MB
    u16*   Qbf    = (u16*)(ws + 71308864);
    u16*   xfT    = (u16*)(ws + 138417728);

    float* out  = (float*)d_out;
    float* WhB  = out;             // 2048*512 scratch inside d_out
    float* hcat = out + 1048576;   // 2048*512 scratch inside d_out

    // ---- conversion (+CSR co-scheduled) + big S GEMM ----
    k_convX<<<1024, 256, 0, stream>>>(x, xfT, adj, deg, idxs);
    k_bigS<<<512, 256, 0, stream>>>(Q, xfT, Qbf, S_part, csPart);
    k_redS<<<1600, 256, 0, stream>>>(S_part, csPart, xn);

    // ---- GNN mid-section: 6 launches ----
    k_wh5<<<dim3(64, 5), 256, 0, stream>>>(xn, gatW, gata, g1aW, WhB, f1, f2, hbuf);
    k_s1ah<<<5120, 256, 0, stream>>>(hbuf, deg, idxs, g1ab, zbuf, WhB, f1, f2, hcat);
    k_g1bO<<<320, 256, 0, stream>>>(zbuf, g1bW, hbuf, hcat, outW, outa, WhO, f1o, f2o);
    k_s2g2a<<<128, 256, 0, stream>>>(hbuf, deg, idxs, g1bb, xn, g2aW, zbuf);
    k_s3g2b<<<128, 256, 0, stream>>>(zbuf, deg, idxs, g2ab, g2bW, hbuf);
    k_s4ao<<<512, 256, 0, stream>>>(hbuf, deg, idxs, g2bb, WhO, f1o, f2o,
                                    Wf, bfp, convw, convb, yT);

    // ---- final projection (overwrites WhB/hcat scratch in d_out) ----
    k_final<<<512, 256, 0, stream>>>(Qbf, yT, out);
}

// Round 17
// 627.206 us; speedup vs baseline: 1.4654x; 1.0132x over previous
//
#include <hip/hip_runtime.h>
#include <math.h>

#define BNF 0.9999950000374997f

constexpr int N    = 2048;
constexpr int C    = 200;
constexpr int HW   = 65536;
constexpr int MAXDEG = 96;

typedef unsigned short u16;
typedef unsigned long long u64;
typedef __attribute__((ext_vector_type(8))) short short8;
typedef __attribute__((ext_vector_type(4))) float f32x4;

union Frag  { short8 v; ushort4 h[2]; };
union FragA { short8 v; uint2 u2[2]; };
union H4Q   { ushort4 h; u64 q; };

__device__ inline u16 f2bf(float x) {
    unsigned int u = __float_as_uint(x);
    unsigned int r = (u + 0x7fffu + ((u >> 16) & 1u)) >> 16;
    return (u16)r;
}

__device__ __forceinline__ void gload16(const void* g, void* l) {
    __builtin_amdgcn_global_load_lds(
        (const __attribute__((address_space(1))) unsigned int*)g,
        (__attribute__((address_space(3))) unsigned int*)l, 16, 0, 0);
}

// ---------------------------------------------------------------------------
// blocks 0..511: xf -> xfT [208][65536] bf16 (rows 200..207 zeroed)
// blocks 512..1023: CSR build
// ---------------------------------------------------------------------------
__global__ __launch_bounds__(256) void k_convX(const float* __restrict__ xf,
                                               u16* __restrict__ xfT,
                                               const float* __restrict__ adj,
                                               int* __restrict__ deg,
                                               int* __restrict__ idxs) {
    const int t = threadIdx.x;
    if (blockIdx.x >= 512) {
        int w = t >> 6, lane = t & 63;
        int n = (blockIdx.x - 512) * 4 + w;
        const float* row = adj + (size_t)n * N;
        int base = 0;
        for (int c = 0; c < N; c += 64) {
            float v = row[c + lane];
            bool p = v > 0.f;
            unsigned long long m = __ballot(p);
            int pos = __popcll(m & ((1ull << lane) - 1ull));
            if (p && (base + pos) < MAXDEG)
                idxs[(size_t)n * MAXDEG + base + pos] = c + lane;
            base += __popcll(m);
        }
        if (lane == 0) deg[n] = base < MAXDEG ? base : MAXDEG;
        return;
    }
    __shared__ __align__(16) u16 T2[200][140];
    const int i0 = blockIdx.x * 128;
    for (int p = 0; p < 25; ++p) {
        int idx = p * 256 + t;
        int il = idx / 50, cq = idx % 50;
        float4 v = *(const float4*)&xf[(size_t)(i0 + il) * 200 + cq * 4];
        T2[cq * 4 + 0][il] = f2bf(v.x);
        T2[cq * 4 + 1][il] = f2bf(v.y);
        T2[cq * 4 + 2][il] = f2bf(v.z);
        T2[cq * 4 + 3][il] = f2bf(v.w);
    }
    __syncthreads();
    for (int p = 0; p < 13; ++p) {
        int c = p * 16 + (t >> 4);
        if (c < 200) {
            int io = (t & 15) * 8;
            u16* dst = &xfT[(size_t)c * 65536 + i0 + io];
            *(ushort4*)&dst[0] = *(const ushort4*)&T2[c][io];
            *(ushort4*)&dst[4] = *(const ushort4*)&T2[c][io + 4];
        }
    }
    ushort4 z4 = {0, 0, 0, 0};
    for (int idx = t; idx < 8 * 16; idx += 256) {
        int r = 200 + (idx >> 4), io = (idx & 15) * 8;
        u16* dst = &xfT[(size_t)r * 65536 + i0 + io];
        *(ushort4*)&dst[0] = z4;
        *(ushort4*)&dst[4] = z4;
    }
}

// ---------------------------------------------------------------------------
// Fused conversion + S-partial GEMM (round-16 proven; + non-temporal stores
// for Qbf/S_part/csPart: write-once streams bypass L2 -> B-slab stays
// L2-resident per XCD).
// ---------------------------------------------------------------------------
__global__ __launch_bounds__(256, 3) void k_bigS(const float* __restrict__ Q,
                                                 const u16* __restrict__ xfT,
                                                 u16* __restrict__ Qbf,
                                                 float* __restrict__ S_part,
                                                 float* __restrict__ csPart) {
    __shared__ __align__(16) u16 Bt[2][208 * 32];
    __shared__ __align__(16) u16 At[64 * 34];
    const int bid = blockIdx.x;
    const int xcd = bid & 7, jb = bid >> 3;          // jb 0..63
    const int nt_b = jb & 31;
    const int ks_b = ((jb >> 5) << 3) + xcd;         // 16 slabs, same-slab -> same XCD
    const int n0 = nt_b * 64;
    const size_t i0 = (size_t)ks_b * 4096;
    const int t = threadIdx.x, w = t >> 6, l = t & 63;
    const int ct0 = (w == 0) ? 0 : (4 + (w - 1) * 3);
    const int nct = (w == 0) ? 4 : 3;
    const int lrowB = l >> 2;
    const int scolB = (((l & 3) ^ ((l >> 3) & 3)) << 3);
    const int nq = t & 15;
    const int kp = t >> 4;

    f32x4 acc[4][4];
#pragma unroll
    for (int a = 0; a < 4; ++a)
#pragma unroll
        for (int b = 0; b < 4; ++b) acc[a][b] = (f32x4){0.f, 0.f, 0.f, 0.f};
    float csum[4] = {0.f, 0.f, 0.f, 0.f};

    float4 aq0, ar0, aq1, ar1;

#define ISSUE_B(PAR, STEP)                                                      \
    {                                                                           \
        const size_t kc = i0 + (size_t)(STEP) * 32 + scolB;                     \
        for (int s = w; s < 13; s += 4)                                         \
            gload16(&xfT[(size_t)(s * 16 + lrowB) * 65536 + kc],                \
                    &Bt[PAR][s * 512]);                                         \
    }

#define LOAD_A(AQ, AR, STEP)                                                    \
    {                                                                           \
        const float* qp = &Q[(i0 + (size_t)(STEP) * 32 + kp * 2) * 2048         \
                             + n0 + nq * 4];                                    \
        AQ = *(const float4*)qp;                                                \
        AR = *(const float4*)(qp + 2048);                                       \
    }

#define WRITE_A(AQ, AR, STEP)                                                   \
    {                                                                           \
        const float* ca = (const float*)&AQ;                                    \
        const float* cb = (const float*)&AR;                                    \
        H4Q s0, s1;                                                             \
        u16* q0 = (u16*)&s0; u16* q1 = (u16*)&s1;                               \
        _Pragma("unroll")                                                       \
        for (int jj = 0; jj < 4; ++jj) {                                        \
            const int n_ = nq * 4 + jj;                                         \
            ushort2 p2;                                                         \
            p2.x = f2bf(ca[jj]); p2.y = f2bf(cb[jj]);                           \
            *(ushort2*)&At[n_ * 34 + ((n_ & 1) << 1) + kp * 2] = p2;            \
            csum[jj] += ca[jj] + cb[jj];                                        \
            q0[jj] = p2.x; q1[jj] = p2.y;                                       \
        }                                                                       \
        const size_t r0 = i0 + (size_t)(STEP) * 32 + kp * 2;                    \
        __builtin_nontemporal_store(s0.q, (u64*)&Qbf[r0 * 2048 + n0 + nq * 4]); \
        __builtin_nontemporal_store(s1.q, (u64*)&Qbf[(r0 + 1) * 2048 + n0 + nq * 4]); \
    }

#define MFMA_PHASE(PAR)                                                         \
    {                                                                           \
        const u16* Bb = Bt[PAR];                                                \
        const int g = l >> 4;                                                   \
        FragA af[4];                                                            \
        _Pragma("unroll")                                                       \
        for (int nt = 0; nt < 4; ++nt) {                                        \
            const int r = nt * 16 + (l & 15);                                   \
            const int ab = r * 34 + ((r & 1) << 1) + g * 8;                     \
            af[nt].u2[0] = *(const uint2*)&At[ab];                              \
            af[nt].u2[1] = *(const uint2*)&At[ab + 4];                          \
        }                                                                       \
        _Pragma("unroll")                                                       \
        for (int c = 0; c < 4; ++c) {                                           \
            if (c < nct) {                                                      \
                const int rb = (ct0 + c) * 16 + (l & 15);                       \
                Frag bf;                                                        \
                bf.v = *(const short8*)&Bb[rb * 32 + ((g ^ ((rb >> 1) & 3)) << 3)]; \
                _Pragma("unroll")                                               \
                for (int nt = 0; nt < 4; ++nt)                                  \
                    acc[nt][c] = __builtin_amdgcn_mfma_f32_16x16x32_bf16(       \
                        af[nt].v, bf.v, acc[nt][c], 0, 0, 0);                   \
            }                                                                   \
        }                                                                       \
    }

#define STEPBODY(STEP, PAR, NPAR, CQ, CR, COND)                                 \
    {                                                                           \
        if (COND) ISSUE_B(NPAR, (STEP) + 1);                                    \
        WRITE_A(CQ, CR, STEP);                                                  \
        {                                                                       \
            const int nst = ((STEP) + 2 > 127) ? 127 : (STEP) + 2;              \
            LOAD_A(CQ, CR, nst);                                                \
        }                                                                       \
        asm volatile("s_waitcnt lgkmcnt(0)" ::: "memory");                      \
        __builtin_amdgcn_s_barrier();                                           \
        if (COND) {                                                             \
            if (w == 0) asm volatile("s_waitcnt vmcnt(12)" ::: "memory");       \
            else        asm volatile("s_waitcnt vmcnt(11)" ::: "memory");       \
        } else {                                                                \
            asm volatile("s_waitcnt vmcnt(0)" ::: "memory");                    \
        }                                                                       \
        MFMA_PHASE(PAR);                                                        \
        __builtin_amdgcn_s_barrier();                                           \
    }

    ISSUE_B(0, 0);
    LOAD_A(aq0, ar0, 0);
    LOAD_A(aq1, ar1, 1);

    for (int s2 = 0; s2 < 64; ++s2) {
        STEPBODY(s2 * 2,     0, 1, aq0, ar0, true);
        STEPBODY(s2 * 2 + 1, 1, 0, aq1, ar1, (s2 < 63));
    }
#undef STEPBODY
#undef MFMA_PHASE
#undef WRITE_A
#undef LOAD_A
#undef ISSUE_B

    __syncthreads();
    float* csF = (float*)At;
#pragma unroll
    for (int jj = 0; jj < 4; ++jj)
        csF[kp * 64 + nq * 4 + jj] = csum[jj];
    __syncthreads();
    if (t < 64) {
        float s = 0.f;
#pragma unroll
        for (int g2 = 0; g2 < 16; ++g2) s += csF[g2 * 64 + t];
        __builtin_nontemporal_store(s, &csPart[(size_t)ks_b * 2048 + n0 + t]);
    }
    float* Sp = S_part + (size_t)ks_b * 409600;
#pragma unroll
    for (int nt = 0; nt < 4; ++nt)
#pragma unroll
        for (int c = 0; c < 4; ++c) {
            if (c < nct) {
                const int cc = (ct0 + c) * 16 + (l & 15);
                if (cc < 200) {
                    const int nbase = n0 + nt * 16 + ((l >> 4) << 2);
#pragma unroll
                    for (int r = 0; r < 4; ++r)
                        __builtin_nontemporal_store(acc[nt][c][r],
                            &Sp[(size_t)(nbase + r) * 200 + cc]);
                }
            }
        }
}

// xn = BN * (sum S_part) / (sum csPart)   (16 slabs)
__global__ void k_redS(const float* __restrict__ S_part, const float* __restrict__ csPart,
                       float* __restrict__ xn) {
    int i = blockIdx.x * 256 + threadIdx.x;
    if (i >= N * C) return;
    int n = i / C;
    float s = 0.f, csn = 0.f;
#pragma unroll 8
    for (int p = 0; p < 16; ++p) s += S_part[(size_t)p * 409600 + i];
#pragma unroll 8
    for (int p = 0; p < 16; ++p) csn += csPart[(size_t)p * 2048 + n];
    xn[i] = BNF * s / csn;
}

// ---------------------------------------------------------------------------
// Merged: z<4 -> GAT Wh head z (+f1/f2 epilogue); z==4 -> GCN mm1 (BNF^2).
// ---------------------------------------------------------------------------
__global__ __launch_bounds__(256) void k_wh5(const float* __restrict__ xn,
                                             const float* __restrict__ gatW,
                                             const float* __restrict__ gata,
                                             const float* __restrict__ g1aW,
                                             float* __restrict__ WhB,
                                             float* __restrict__ f1,
                                             float* __restrict__ f2,
                                             float* __restrict__ hbuf) {
    __shared__ float ldsA[32][33];
    __shared__ float ldsW[32][128];
    __shared__ float ldsWh[32][129];
    const int rt = blockIdx.x * 32;
    const int z  = blockIdx.y;
    const bool gat = z < 4;
    const float* Wp = gat ? gatW + (size_t)z * 25600 : g1aW;
    const int t = threadIdx.x;
    const int col = t & 127, rg = t >> 7;
    float acc[16];
#pragma unroll
    for (int r = 0; r < 16; ++r) acc[r] = 0.f;

    for (int k0 = 0; k0 < 200; k0 += 32) {
        for (int idx = t; idx < 32 * 32; idx += 256) {
            int r = idx >> 5, kk = idx & 31;
            int k = k0 + kk;
            ldsA[r][kk] = (k < 200) ? xn[(size_t)(rt + r) * 200 + k] : 0.f;
        }
        for (int idx = t; idx < 32 * 128; idx += 256) {
            int kk = idx >> 7, c = idx & 127;
            int k = k0 + kk;
            ldsW[kk][c] = (k < 200) ? Wp[(size_t)k * 128 + c] : 0.f;
        }
        __syncthreads();
#pragma unroll 8
        for (int kk = 0; kk < 32; ++kk) {
            float wv = ldsW[kk][col];
#pragma unroll
            for (int r = 0; r < 16; ++r) acc[r] += ldsA[rg * 16 + r][kk] * wv;
        }
        __syncthreads();
    }
    if (gat) {
#pragma unroll
        for (int r = 0; r < 16; ++r) {
            ldsWh[rg * 16 + r][col] = acc[r];
            WhB[(size_t)(rt + rg * 16 + r) * 512 + z * 128 + col] = acc[r];
        }
        __syncthreads();
        int row = t >> 3, p = t & 7;
        const float* a = gata + z * 256;
        float s1 = 0.f, s2 = 0.f;
#pragma unroll
        for (int j = 0; j < 16; ++j) {
            int c = p * 16 + j;
            float v = ldsWh[row][c];
            s1 += v * a[c]; s2 += v * a[128 + c];
        }
        s1 += __shfl_xor(s1, 1); s1 += __shfl_xor(s1, 2); s1 += __shfl_xor(s1, 4);
        s2 += __shfl_xor(s2, 1); s2 += __shfl_xor(s2, 2); s2 += __shfl_xor(s2, 4);
        if (p == 0) { f1[z * N + rt + row] = s1; f2[z * N + rt + row] = s2; }
    } else {
        const float sc = BNF * BNF;
#pragma unroll
        for (int r = 0; r < 16; ++r)
            hbuf[(size_t)(rt + rg * 16 + r) * 128 + col] = sc * acc[r];
    }
}

// ---------------------------------------------------------------------------
// Merged: vb<1024 -> spmm1 (W=128); else -> att_head (2 per block).
// ---------------------------------------------------------------------------
__global__ void k_s1ah(const float* __restrict__ hbuf, const int* __restrict__ deg,
                       const int* __restrict__ idxs, const float* __restrict__ g1ab,
                       float* __restrict__ zbuf, const float* __restrict__ WhB,
                       const float* __restrict__ f1, const float* __restrict__ f2,
                       float* __restrict__ hcat) {
    __shared__ float eW[256];
    const int vb = blockIdx.x;
    const int t = threadIdx.x;
    if (vb < 1024) {
        const int n = vb * 2 + (t >> 7), k = t & 127;
        const int d = deg[n];
        const int* row = idxs + (size_t)n * MAXDEG;
        float a = 0.f;
        for (int j = 0; j < d; ++j) a += hbuf[(size_t)row[j] * 128 + k];
        float v = a + g1ab[k];
        v = v >= 0.f ? v : 0.01f * v;
        zbuf[(size_t)n * 128 + k] = v;
    } else {
        const int va = vb - 1024;
        const int half = t >> 7, k = t & 127;
        const int u = va * 2 + half;
        const int h = u >> 11, n = u & 2047;
        const int d = deg[n];
        const int* row = idxs + (size_t)n * MAXDEG;
        const float f1v = f1[h * N + n];
        const float* f2h = f2 + h * N;
        float* e = eW + half * 128;
        if (k < d) {
            float ev = f1v + f2h[row[k]];
            e[k] = ev >= 0.f ? ev : 0.2f * ev;
        }
        __syncthreads();
        float mx = -1e30f;
        for (int j = 0; j < d; ++j) mx = fmaxf(mx, e[j]);
        __syncthreads();
        if (k < d) e[k] = __expf(e[k] - mx);
        __syncthreads();
        float ssum = 0.f, acc = 0.f;
        for (int j = 0; j < d; ++j) ssum += e[j];
        for (int j = 0; j < d; ++j)
            acc += e[j] * WhB[(size_t)row[j] * 512 + h * 128 + k];
        float v = acc / ssum;
        v = v > 0.f ? v : __expf(v) - 1.f;
        hcat[(size_t)n * 512 + h * 128 + k] = v;
    }
}

// ---------------------------------------------------------------------------
// Merged: vb<256 -> mm g1b (zbuf@g1bW -> hbuf200); else -> mmO (+f1o/f2o).
// ---------------------------------------------------------------------------
__global__ __launch_bounds__(256) void k_g1bO(const float* __restrict__ zbuf,
                                              const float* __restrict__ g1bW,
                                              float* __restrict__ hbuf,
                                              const float* __restrict__ hcat,
                                              const float* __restrict__ outW,
                                              const float* __restrict__ outa,
                                              float* __restrict__ WhO,
                                              float* __restrict__ f1o,
                                              float* __restrict__ f2o) {
    __shared__ float ldsA[32][33];
    __shared__ float ldsW[32][65];
    const int vb = blockIdx.x;
    const int t = threadIdx.x;
    const int lane = t & 63, wg = t >> 6;
    float acc[8];
#pragma unroll
    for (int r = 0; r < 8; ++r) acc[r] = 0.f;

    if (vb < 256) {
        const int rt = (vb & 63) * 32, ct = (vb >> 6) * 64;
        for (int k0 = 0; k0 < 128; k0 += 32) {
            for (int idx = t; idx < 1024; idx += 256) {
                int r = idx >> 5, kk = idx & 31;
                ldsA[r][kk] = zbuf[(size_t)(rt + r) * 128 + k0 + kk];
            }
            for (int idx = t; idx < 2048; idx += 256) {
                int kk = idx >> 6, c = idx & 63;
                int cg = ct + c;
                ldsW[kk][c] = (cg < 200) ? g1bW[(size_t)(k0 + kk) * 200 + cg] : 0.f;
            }
            __syncthreads();
#pragma unroll 8
            for (int kk = 0; kk < 32; ++kk) {
                float wv = ldsW[kk][lane];
#pragma unroll
                for (int r = 0; r < 8; ++r) acc[r] += ldsA[wg * 8 + r][kk] * wv;
            }
            __syncthreads();
        }
        int cg = ct + lane;
        if (cg < 200) {
#pragma unroll
            for (int r = 0; r < 8; ++r)
                hbuf[(size_t)(rt + wg * 8 + r) * 200 + cg] = BNF * acc[r];
        }
    } else {
        const int rt = (vb - 256) * 32;
        for (int k0 = 0; k0 < 512; k0 += 32) {
            for (int idx = t; idx < 1024; idx += 256) {
                int r = idx >> 5, kk = idx & 31;
                ldsA[r][kk] = hcat[(size_t)(rt + r) * 512 + k0 + kk];
            }
            for (int idx = t; idx < 2048; idx += 256) {
                int kk = idx >> 6, c = idx & 63;
                ldsW[kk][c] = outW[(size_t)(k0 + kk) * 64 + c];
            }
            __syncthreads();
#pragma unroll 8
            for (int kk = 0; kk < 32; ++kk) {
                float wv = ldsW[kk][lane];
#pragma unroll
                for (int r = 0; r < 8; ++r) acc[r] += ldsA[wg * 8 + r][kk] * wv;
            }
            __syncthreads();
        }
#pragma unroll
        for (int r = 0; r < 8; ++r)
            WhO[(size_t)(rt + wg * 8 + r) * 64 + lane] = acc[r];
#pragma unroll
        for (int r = 0; r < 8; ++r) {
            float v1 = acc[r] * outa[lane];
            float v2 = acc[r] * outa[64 + lane];
#pragma unroll
            for (int off = 32; off; off >>= 1) {
                v1 += __shfl_down(v1, off);
                v2 += __shfl_down(v2, off);
            }
            if (lane == 0) { f1o[rt + wg * 8 + r] = v1; f2o[rt + wg * 8 + r] = v2; }
        }
    }
}

// ---------------------------------------------------------------------------
// Fused spmm2 + mm g2a: 16 rows/block (grid 128). xg2 kept in LDS.
// ---------------------------------------------------------------------------
__global__ __launch_bounds__(256) void k_s2g2a(const float* __restrict__ hbuf,
                                               const int* __restrict__ deg,
                                               const int* __restrict__ idxs,
                                               const float* __restrict__ g1bb,
                                               const float* __restrict__ xn,
                                               const float* __restrict__ g2aW,
                                               float* __restrict__ outp) {
    __shared__ float X[16][204];
    __shared__ float ldsW[32][128];
    const int rt = blockIdx.x * 16;
    const int t = threadIdx.x;
    {
        const int row = t >> 4, tc = t & 15;
        const int n = rt + row;
        const int d = deg[n];
        const int* rp = idxs + (size_t)n * MAXDEG;
        float a[13];
#pragma unroll
        for (int c = 0; c < 13; ++c) a[c] = 0.f;
        for (int j = 0; j < d; ++j) {
            const float* hr = hbuf + (size_t)rp[j] * 200;
#pragma unroll
            for (int c = 0; c < 13; ++c) {
                int col = tc + 16 * c;
                if (col < 200) a[c] += hr[col];
            }
        }
#pragma unroll
        for (int c = 0; c < 13; ++c) {
            int col = tc + 16 * c;
            if (col < 200) {
                float v = BNF * (a[c] + g1bb[col]);
                v = v >= 0.f ? v : 0.01f * v;
                v += BNF * xn[(size_t)n * 200 + col];
                X[row][col] = v;
            }
        }
    }
    __syncthreads();
    const int col = t & 127, rg = t >> 7;
    float acc[8];
#pragma unroll
    for (int r = 0; r < 8; ++r) acc[r] = 0.f;
    for (int k0 = 0; k0 < 200; k0 += 32) {
        for (int idx = t; idx < 4096; idx += 256) {
            int kk = idx >> 7, c = idx & 127;
            int k = k0 + kk;
            ldsW[kk][c] = (k < 200) ? g2aW[(size_t)k * 128 + c] : 0.f;
        }
        __syncthreads();
#pragma unroll 8
        for (int kk = 0; kk < 32; ++kk) {
            if (k0 + kk < 200) {
                float wv = ldsW[kk][col];
#pragma unroll
                for (int r = 0; r < 8; ++r) acc[r] += X[rg * 8 + r][k0 + kk] * wv;
            }
        }
        __syncthreads();
    }
#pragma unroll
    for (int r = 0; r < 8; ++r)
        outp[(size_t)(rt + rg * 8 + r) * 128 + col] = BNF * acc[r];
}

// ---------------------------------------------------------------------------
// Fused spmm3 + mm g2b: 16 rows/block (grid 128). z kept in LDS.
// ---------------------------------------------------------------------------
__global__ __launch_bounds__(256) void k_s3g2b(const float* __restrict__ inp,
                                               const int* __restrict__ deg,
                                               const int* __restrict__ idxs,
                                               const float* __restrict__ g2ab,
                                               const float* __restrict__ g2bW,
                                               float* __restrict__ outp) {
    __shared__ float Z[16][132];
    __shared__ float ldsW[32][65];
    const int rt = blockIdx.x * 16;
    const int t = threadIdx.x;
    {
        const int row = t >> 4, tc = t & 15;
        const int n = rt + row;
        const int d = deg[n];
        const int* rp = idxs + (size_t)n * MAXDEG;
        float a[8];
#pragma unroll
        for (int c = 0; c < 8; ++c) a[c] = 0.f;
        for (int j = 0; j < d; ++j) {
            const float* hr = inp + (size_t)rp[j] * 128;
#pragma unroll
            for (int c = 0; c < 8; ++c) a[c] += hr[tc + 16 * c];
        }
#pragma unroll
        for (int c = 0; c < 8; ++c) {
            int col = tc + 16 * c;
            float v = a[c] + g2ab[col];
            Z[row][col] = v >= 0.f ? v : 0.01f * v;
        }
    }
    __syncthreads();
    const int lane = t & 63, wg = t >> 6;
    float acc[4];
#pragma unroll
    for (int r = 0; r < 4; ++r) acc[r] = 0.f;
    for (int k0 = 0; k0 < 128; k0 += 32) {
        for (int idx = t; idx < 2048; idx += 256) {
            int kk = idx >> 6, c = idx & 63;
            ldsW[kk][c] = g2bW[(size_t)(k0 + kk) * 64 + c];
        }
        __syncthreads();
#pragma unroll 8
        for (int kk = 0; kk < 32; ++kk) {
            float wv = ldsW[kk][lane];
#pragma unroll
            for (int r = 0; r < 4; ++r) acc[r] += Z[wg * 4 + r][k0 + kk] * wv;
        }
        __syncthreads();
    }
#pragma unroll
    for (int r = 0; r < 4; ++r)
        outp[(size_t)(rt + wg * 4 + r) * 64 + lane] = BNF * acc[r];
}

// ---------------------------------------------------------------------------
// Fused spmm4 + att_out + fusion: 4 nodes/block (grid 512). GCNx in register.
// ---------------------------------------------------------------------------
__global__ void k_s4ao(const float* __restrict__ h64, const int* __restrict__ deg,
                       const int* __restrict__ idxs, const float* __restrict__ g2bb,
                       const float* __restrict__ WhO, const float* __restrict__ f1o,
                       const float* __restrict__ f2o,
                       const float* __restrict__ Wf, const float* __restrict__ bfp,
                       const float* __restrict__ cw, const float* __restrict__ cb,
                       u16* __restrict__ yT) {
    __shared__ float eW[4][MAXDEG];
    const int sub = threadIdx.x >> 6, k = threadIdx.x & 63;
    const int n = blockIdx.x * 4 + sub;
    const int d = deg[n];
    const int* row = idxs + (size_t)n * MAXDEG;
    float a = 0.f;
    for (int j = 0; j < d; ++j) a += h64[(size_t)row[j] * 64 + k];
    float g = a + g2bb[k];
    g = g >= 0.f ? g : 0.01f * g;
    g *= BNF;
    const float f1v = f1o[n];
    float* e = eW[sub];
    for (int j = k; j < d; j += 64) {
        float ev = f1v + f2o[row[j]];
        e[j] = ev >= 0.f ? ev : 0.2f * ev;
    }
    __syncthreads();
    float mx = -1e30f;
    for (int j = 0; j < d; ++j) mx = fmaxf(mx, e[j]);
    __syncthreads();
    for (int j = k; j < d; j += 64) e[j] = __expf(e[j] - mx);
    __syncthreads();
    float ssum = 0.f, acc = 0.f;
    for (int j = 0; j < d; ++j) ssum += e[j];
    for (int j = 0; j < d; ++j) acc += e[j] * WhO[(size_t)row[j] * 64 + k];
    float v = acc / ssum;
    v = v > 0.f ? v : __expf(v) - 1.f;   // elu
    v *= BNF;
    float gat = v >= 0.f ? v : 0.01f * v;
    float mn = fminf(g, gat), mxv = fmaxf(g, gat);
    float avg = g * Wf[k] + bfp[k] + gat * Wf[64 + k] + bfp[64 + k];
    float base = g + gat;
    float yv = cw[0] * (mn + base) + cw[1] * (mxv + base) + cw[2] * (avg + base) + cb[0];
    yv *= BNF;
    yv = yv >= 0.f ? yv : 0.2f * yv;
    yT[k * 2048 + n] = f2bf(yv);
}

// ---------------------------------------------------------------------------
// out[i,f] = sum_n Qbf[i,n]*yT[f,n] (round-10 proven, unchanged).
// ---------------------------------------------------------------------------
__global__ __launch_bounds__(256, 2) void k_final(const u16* __restrict__ Qbf,
                                                  const u16* __restrict__ yT,
                                                  float* __restrict__ out) {
    __shared__ __align__(16) u16 Aq[3][128 * 64];
    __shared__ __align__(16) u16 By[3][64 * 64];
    const int i0 = blockIdx.x * 128;
    const int t = threadIdx.x, w = t >> 6, l = t & 63;
    const int lrow = l >> 3;
    const int scol = (((l & 7) ^ ((l >> 3) & 7)) << 3);
    f32x4 acc[2][4];
#pragma unroll
    for (int a = 0; a < 2; ++a)
#pragma unroll
        for (int b = 0; b < 4; ++b) acc[a][b] = (f32x4){0.f, 0.f, 0.f, 0.f};

#define STAGE_F(buf, step)                                                          \
    {                                                                               \
        const size_t kc = (size_t)(step) * 64 + scol;                               \
        for (int s = w; s < 16; s += 4)                                             \
            gload16(&Qbf[(size_t)(i0 + s * 8 + lrow) * 2048 + kc],                  \
                    &Aq[buf][s * 512]);                                             \
        for (int s = w; s < 8; s += 4)                                              \
            gload16(&yT[(size_t)(s * 8 + lrow) * 2048 + kc],                        \
                    &By[buf][s * 512]);                                             \
    }

    STAGE_F(0, 0);
    STAGE_F(1, 1);
    for (int step = 0; step < 32; ++step) {
        const int cur = step % 3;
        if (step + 2 < 32) STAGE_F((step + 2) % 3, step + 2);
        if (step + 2 < 32)      asm volatile("s_waitcnt vmcnt(12)" ::: "memory");
        else if (step + 1 < 32) asm volatile("s_waitcnt vmcnt(6)"  ::: "memory");
        else                    asm volatile("s_waitcnt vmcnt(0)"  ::: "memory");
        __builtin_amdgcn_s_barrier();

        const u16* Ab = Aq[cur];
        const u16* Bb = By[cur];
#pragma unroll
        for (int sub = 0; sub < 2; ++sub) {
            const int c8 = sub * 4 + (l >> 4);
            Frag a[2];
#pragma unroll
            for (int it = 0; it < 2; ++it) {
                const int r = w * 32 + it * 16 + (l & 15);
                a[it].v = *(const short8*)&Ab[r * 64 + ((c8 ^ (r & 7)) << 3)];
            }
#pragma unroll
            for (int ft = 0; ft < 4; ++ft) {
                const int rb = ft * 16 + (l & 15);
                Frag b;
                b.v = *(const short8*)&Bb[rb * 64 + ((c8 ^ (rb & 7)) << 3)];
#pragma unroll
                for (int it = 0; it < 2; ++it)
                    acc[it][ft] = __builtin_amdgcn_mfma_f32_16x16x32_bf16(
                        a[it].v, b.v, acc[it][ft], 0, 0, 0);
            }
        }
        asm volatile("s_waitcnt lgkmcnt(0)" ::: "memory");
        __builtin_amdgcn_s_barrier();
    }
#undef STAGE_F
#pragma unroll
    for (int it = 0; it < 2; ++it)
#pragma unroll
        for (int ft = 0; ft < 4; ++ft) {
            const int i = i0 + w * 32 + it * 16 + ((l >> 4) << 2);
            const int f = ft * 16 + (l & 15);
#pragma unroll
            for (int r = 0; r < 4; ++r)
                out[(size_t)(i + r) * 64 + f] = acc[it][ft][r];
        }
}

extern "C" void kernel_launch(void* const* d_in, const int* in_sizes, int n_in,
                              void* d_out, int out_size, void* d_ws, size_t ws_size,
                              hipStream_t stream) {
    const float* x     = (const float*)d_in[0];
    const float* adj   = (const float*)d_in[1];
    const float* Q     = (const float*)d_in[2];
    const float* g1aW  = (const float*)d_in[3];
    const float* g1ab  = (const float*)d_in[4];
    const float* g1bW  = (const float*)d_in[5];
    const float* g1bb  = (const float*)d_in[6];
    const float* g2aW  = (const float*)d_in[7];
    const float* g2ab  = (const float*)d_in[8];
    const float* g2bW  = (const float*)d_in[9];
    const float* g2bb  = (const float*)d_in[10];
    const float* gatW  = (const float*)d_in[11];
    const float* gata  = (const float*)d_in[12];
    const float* outW  = (const float*)d_in[13];
    const float* outa  = (const float*)d_in[14];
    const float* Wf    = (const float*)d_in[15];
    const float* bfp   = (const float*)d_in[16];
    const float* convw = (const float*)d_in[17];
    const float* convb = (const float*)d_in[18];

    float* ws   = (float*)d_ws;
    float* xn   = ws + 411648;
    float* hbuf = ws + 1640448;
    float* zbuf = ws + 2050048;
    float* WhO  = ws + 2312192;
    float* f1   = ws + 2836480;
    float* f2   = ws + 2844672;
    float* f1o  = ws + 2852864;
    float* f2o  = ws + 2854912;
    int*   deg  = (int*)(ws + 2856960);
    int*   idxs = (int*)(ws + 2859008);   // ends 3055616
    u16*   yT   = (u16*)(ws + 3300000);
    float* csPart = ws + 3600000;         // 16*2048 f32
    float* S_part = ws + 4200000;         // 16*409600 f32 = 26 MB
    u16*   Qbf    = (u16*)(ws + 71308864);
    u16*   xfT    = (u16*)(ws + 138417728);

    float* out  = (float*)d_out;
    float* WhB  = out;             // 2048*512 scratch inside d_out
    float* hcat = out + 1048576;   // 2048*512 scratch inside d_out

    // ---- conversion (+CSR co-scheduled) + big S GEMM ----
    k_convX<<<1024, 256, 0, stream>>>(x, xfT, adj, deg, idxs);
    k_bigS<<<512, 256, 0, stream>>>(Q, xfT, Qbf, S_part, csPart);
    k_redS<<<1600, 256, 0, stream>>>(S_part, csPart, xn);

    // ---- GNN mid-section: 6 launches ----
    k_wh5<<<dim3(64, 5), 256, 0, stream>>>(xn, gatW, gata, g1aW, WhB, f1, f2, hbuf);
    k_s1ah<<<5120, 256, 0, stream>>>(hbuf, deg, idxs, g1ab, zbuf, WhB, f1, f2, hcat);
    k_g1bO<<<320, 256, 0, stream>>>(zbuf, g1bW, hbuf, hcat, outW, outa, WhO, f1o, f2o);
    k_s2g2a<<<128, 256, 0, stream>>>(hbuf, deg, idxs, g1bb, xn, g2aW, zbuf);
    k_s3g2b<<<128, 256, 0, stream>>>(zbuf, deg, idxs, g2ab, g2bW, hbuf);
    k_s4ao<<<512, 256, 0, stream>>>(hbuf, deg, idxs, g2bb, WhO, f1o, f2o,
                                    Wf, bfp, convw, convb, yT);

    // ---- final projection (overwrites WhB/hcat scratch in d_out) ----
    k_final<<<512, 256, 0, stream>>>(Qbf, yT, out);
}